// Round 1
// baseline (4918.632 us; speedup 1.0000x reference)
//
#include <hip/hip_runtime.h>
#include <stdint.h>

#define SS 512
#define BB 64
#define HH 256
#define TT 32

typedef __attribute__((ext_vector_type(8))) short bf16x8;
typedef __attribute__((ext_vector_type(4))) short short4v;
typedef __attribute__((ext_vector_type(4))) float f32x4;

__device__ __forceinline__ unsigned short f2bf(float f){
  unsigned u = __float_as_uint(f);
  unsigned r = (u + 0x7FFFu + ((u >> 16) & 1u)) >> 16;
  return (unsigned short)r;
}
__device__ __forceinline__ float bf2f(unsigned short s){
  return __uint_as_float(((unsigned)s) << 16);
}
__device__ __forceinline__ float sigm(float x){ return 1.0f/(1.0f+__expf(-x)); }

// ---------------- embedding gather: [V][H] f32 -> [t][b][H] bf16 ----------------
__global__ void k_gather(const int* __restrict__ seq, const float* __restrict__ emb,
                         unsigned short* __restrict__ out)
{
  int gid = blockIdx.x*256 + threadIdx.x;         // SS*BB*(HH/8) threads
  int h8 = gid & 31; int b = (gid >> 5) & 63; int t = gid >> 11;
  int row = seq[b*SS + t];
  const float* s = emb + (size_t)row*HH + h8*8;
  float4 x0 = *(const float4*)s;
  float4 x1 = *(const float4*)(s+4);
  union { unsigned short u[8]; uint4 v; } o;
  o.u[0]=f2bf(x0.x); o.u[1]=f2bf(x0.y); o.u[2]=f2bf(x0.z); o.u[3]=f2bf(x0.w);
  o.u[4]=f2bf(x1.x); o.u[5]=f2bf(x1.y); o.u[6]=f2bf(x1.z); o.u[7]=f2bf(x1.w);
  *(uint4*)(out + (size_t)(t*BB + b)*HH + h8*8) = o.v;
}

// A-fragment read from swizzled LDS tile [64 rows][256 cols] bf16.
// k-map convention (elems 0-3 -> k = 4*kq+j, elems 4-7 -> k+16) is applied
// identically to A and B fragments, so any bijective k-permutation cancels.
__device__ __forceinline__ bf16x8 afrag(const unsigned short* A, int mt, int ktp, int nl, int kq){
  int m = mt*16 + nl;
  int sw = (m & 7) << 3;
  int kk = ktp*32 + kq*4;
  short4v lo = *(const short4v*)(A + (m << 8) + (kk ^ sw));
  short4v hi = *(const short4v*)(A + (m << 8) + ((kk + 16) ^ sw));
  bf16x8 r = {lo[0],lo[1],lo[2],lo[3],hi[0],hi[1],hi[2],hi[3]};
  return r;
}

// ---------------- persistent bidirectional LSTM ----------------
// 32 blocks: blocks 0..15 = forward, 16..31 = backward. Block wg owns gate
// columns {wg*16..+15} of each of the 4 gates (wave w = gate chunk w).
__global__ __launch_bounds__(256,1) void k_lstm(
    const unsigned short* __restrict__ embq,
    const float* __restrict__ Wih_f, const float* __restrict__ Whh_f,
    const float* __restrict__ bih_f, const float* __restrict__ bhh_f,
    const float* __restrict__ Wih_b, const float* __restrict__ Whh_b,
    const float* __restrict__ bih_b, const float* __restrict__ bhh_b,
    unsigned short* __restrict__ hf, unsigned short* __restrict__ hb,
    unsigned int* cnt)
{
  __shared__ __align__(16) unsigned short A_lds[64*256];   // 32 KiB staged operand tile
  __shared__ __align__(16) float g_lds[4][64][20];         // gate exchange, padded

  const int tid  = threadIdx.x;
  const int lane = tid & 63;
  const int w    = tid >> 6;           // wave = gate chunk (i,f,g,o)
  const int dir  = blockIdx.x >> 4;
  const int wg   = blockIdx.x & 15;

  const float* Wih = dir ? Wih_b : Wih_f;
  const float* Whh = dir ? Whh_b : Whh_f;
  const float* bih = dir ? bih_b : bih_f;
  const float* bhh = dir ? bhh_b : bhh_f;
  unsigned short* hbuf = dir ? hb : hf;
  unsigned int* mycnt = cnt + dir*SS;

  const int nl = lane & 15;
  const int kq = lane >> 4;
  const int ncol = w*256 + wg*16 + nl;   // global gate column (0..1023)

  // B-fragments for combined [Wih; Whh] (K=512), kept in VGPRs (64 regs/lane)
  bf16x8 wf[16];
#pragma unroll
  for (int kt = 0; kt < 16; ++kt){
    int kb = kt*32 + kq*4;
    const float* Wsrc = (kb < 256) ? Wih : Whh;
    int kk = kb & 255;
    const float* p = Wsrc + (size_t)ncol*HH + kk;
    float4 lo = *(const float4*)p;
    float4 hi = *(const float4*)(p + 16);
    bf16x8 f;
    f[0]=(short)f2bf(lo.x); f[1]=(short)f2bf(lo.y); f[2]=(short)f2bf(lo.z); f[3]=(short)f2bf(lo.w);
    f[4]=(short)f2bf(hi.x); f[5]=(short)f2bf(hi.y); f[6]=(short)f2bf(hi.z); f[7]=(short)f2bf(hi.w);
    wf[kt] = f;
  }
  const float bias = bih[ncol] + bhh[ncol];

  // persistent c-state: thread -> batch row cb, h-cols [cj..cj+3] of this wg's 16
  float c0=0.f, c1=0.f, c2=0.f, c3=0.f;
  const int cb = tid >> 2;
  const int cj = (tid & 3) * 4;

  for (int s = 0; s < SS; ++s){
    const int t = dir ? (SS-1-s) : s;

    { // stage xt = embq[t] (swizzled)
      const unsigned short* src = embq + (size_t)t*BB*HH;
#pragma unroll
      for (int i = 0; i < 8; ++i){
        int c = tid + i*256; int m = c >> 5, k8 = c & 31;
        uint4 v = *(const uint4*)(src + m*HH + k8*8);
        *(uint4*)&A_lds[(m << 8) + ((k8*8) ^ ((m & 7) << 3))] = v;
      }
    }
    __syncthreads();

    f32x4 acc0 = {bias,bias,bias,bias};
    f32x4 acc1 = acc0, acc2 = acc0, acc3 = acc0;
#pragma unroll
    for (int kt = 0; kt < 8; ++kt){   // xt @ Wih^T part
      bf16x8 wv = wf[kt];
      acc0 = __builtin_amdgcn_mfma_f32_16x16x32_bf16(afrag(A_lds,0,kt,nl,kq), wv, acc0, 0,0,0);
      acc1 = __builtin_amdgcn_mfma_f32_16x16x32_bf16(afrag(A_lds,1,kt,nl,kq), wv, acc1, 0,0,0);
      acc2 = __builtin_amdgcn_mfma_f32_16x16x32_bf16(afrag(A_lds,2,kt,nl,kq), wv, acc2, 0,0,0);
      acc3 = __builtin_amdgcn_mfma_f32_16x16x32_bf16(afrag(A_lds,3,kt,nl,kq), wv, acc3, 0,0,0);
    }

    // wait for all 16 WGs of this direction to publish h of step s-1
    if (s > 0 && tid == 0){
      int guard = 0;
      while (__hip_atomic_load(mycnt + (s-1), __ATOMIC_ACQUIRE, __HIP_MEMORY_SCOPE_AGENT) < 16u){
        __builtin_amdgcn_s_sleep(1);
        if (++guard > (1 << 20)) break;   // anti-hang bailout (diagnosable)
      }
    }
    __syncthreads();

    { // stage h_prev (swizzled)
      const int slot = dir ? (t + 1) : s;
      const unsigned short* src = hbuf + (size_t)slot*BB*HH;
#pragma unroll
      for (int i = 0; i < 8; ++i){
        int c = tid + i*256; int m = c >> 5, k8 = c & 31;
        uint4 v = *(const uint4*)(src + m*HH + k8*8);
        *(uint4*)&A_lds[(m << 8) + ((k8*8) ^ ((m & 7) << 3))] = v;
      }
    }
    __syncthreads();

#pragma unroll
    for (int kt = 8; kt < 16; ++kt){  // h @ Whh^T part
      bf16x8 wv = wf[kt];
      acc0 = __builtin_amdgcn_mfma_f32_16x16x32_bf16(afrag(A_lds,0,kt-8,nl,kq), wv, acc0, 0,0,0);
      acc1 = __builtin_amdgcn_mfma_f32_16x16x32_bf16(afrag(A_lds,1,kt-8,nl,kq), wv, acc1, 0,0,0);
      acc2 = __builtin_amdgcn_mfma_f32_16x16x32_bf16(afrag(A_lds,2,kt-8,nl,kq), wv, acc2, 0,0,0);
      acc3 = __builtin_amdgcn_mfma_f32_16x16x32_bf16(afrag(A_lds,3,kt-8,nl,kq), wv, acc3, 0,0,0);
    }

    { // publish gates to LDS: C/D map col=lane&15, row=(lane>>4)*4+reg (HW-verified)
      int rb = kq*4;
#pragma unroll
      for (int r = 0; r < 4; ++r){
        g_lds[w][ 0 + rb + r][nl] = acc0[r];
        g_lds[w][16 + rb + r][nl] = acc1[r];
        g_lds[w][32 + rb + r][nl] = acc2[r];
        g_lds[w][48 + rb + r][nl] = acc3[r];
      }
    }
    __syncthreads();

    { // gate combine + c/h update (lane-local fixed mapping across steps)
      f32x4 ig = *(const f32x4*)&g_lds[0][cb][cj];
      f32x4 fg = *(const f32x4*)&g_lds[1][cb][cj];
      f32x4 gg = *(const f32x4*)&g_lds[2][cb][cj];
      f32x4 og = *(const f32x4*)&g_lds[3][cb][cj];
      union { unsigned short u[4]; uint2 v; } hv;
      float cc;
      cc = sigm(fg[0])*c0 + sigm(ig[0])*tanhf(gg[0]); c0 = cc; hv.u[0] = f2bf(sigm(og[0])*tanhf(cc));
      cc = sigm(fg[1])*c1 + sigm(ig[1])*tanhf(gg[1]); c1 = cc; hv.u[1] = f2bf(sigm(og[1])*tanhf(cc));
      cc = sigm(fg[2])*c2 + sigm(ig[2])*tanhf(gg[2]); c2 = cc; hv.u[2] = f2bf(sigm(og[2])*tanhf(cc));
      cc = sigm(fg[3])*c3 + sigm(ig[3])*tanhf(gg[3]); c3 = cc; hv.u[3] = f2bf(sigm(og[3])*tanhf(cc));
      const int slotw = dir ? t : (s + 1);
      *(uint2*)(hbuf + (size_t)slotw*BB*HH + cb*HH + wg*16 + cj) = hv.v;
    }
    __syncthreads();
    if (tid == 0){
      __hip_atomic_fetch_add(mycnt + s, 1u, __ATOMIC_RELEASE, __HIP_MEMORY_SCOPE_AGENT);
    }
  }
}

// ---------------- FC: logits[t][b][tag] = [hf(t+1);hb(t)] . fcW[tag] + fcb ----------------
__global__ void k_fc(const unsigned short* __restrict__ hf, const unsigned short* __restrict__ hb,
                     const float* __restrict__ fcW, const float* __restrict__ fcb,
                     float* __restrict__ logits)
{
  __shared__ unsigned short WT[512*32];   // fcW transposed [k][tag] bf16
  int tid = threadIdx.x;
  for (int i = tid; i < 512*32; i += 256){
    int k = i >> 5, tg = i & 31;
    WT[i] = f2bf(fcW[tg*512 + k]);
  }
  __syncthreads();
  int lane = tid & 63, w = tid >> 6;
  int grp = lane >> 5, tg = lane & 31;
  float bias = fcb[tg];
  for (int p = 0; p < 8; ++p){
    int pair = (blockIdx.x*4 + w)*8 + p;          // 32768 (t,b) pairs
    int t = pair >> 6, b = pair & 63;
    const unsigned short* xr = grp ? (hb + (size_t)t*BB*HH + b*HH)
                                   : (hf + (size_t)(t+1)*BB*HH + b*HH);
    float acc = 0.f;
    for (int k8 = 0; k8 < 32; ++k8){
      union { uint4 v; unsigned short u[8]; } xu;
      xu.v = *(const uint4*)(xr + k8*8);
      const unsigned short* wrow = WT + (grp*256 + k8*8)*32 + tg;
#pragma unroll
      for (int q = 0; q < 8; ++q) acc += bf2f(xu.u[q]) * bf2f(wrow[q*32]);
    }
    acc += __shfl_xor(acc, 32);
    if (!grp) logits[(size_t)(t*BB + b)*TT + tg] = acc + bias;
  }
}

// ---------------- CRF denominator (logsumexp scan), wave per batch ----------------
__global__ void k_den(const float* __restrict__ logits, const int* __restrict__ mask,
                      const float* __restrict__ start, const float* __restrict__ endt,
                      const float* __restrict__ trans, float* __restrict__ den)
{
  __shared__ float tr[1024];
  int tid = threadIdx.x;
  for (int i = tid; i < 1024; i += 256) tr[i] = trans[i];
  __syncthreads();
  int lane = tid & 63, w = tid >> 6;
  int b = blockIdx.x*4 + w;
  int grp = lane >> 5, tp = lane & 31;
  float score = start[tp] + logits[(size_t)b*TT + tp];
  for (int s = 1; s < SS; ++s){
    float m = -1e30f;
#pragma unroll
    for (int jj = 0; jj < 16; ++jj){
      int j = grp*16 + jj;
      float v = __shfl(score, j) + tr[j*32 + tp];
      m = fmaxf(m, v);
    }
    m = fmaxf(m, __shfl_xor(m, 32));
    float ssum = 0.f;
#pragma unroll
    for (int jj = 0; jj < 16; ++jj){
      int j = grp*16 + jj;
      float v = __shfl(score, j) + tr[j*32 + tp];
      ssum += __expf(v - m);
    }
    ssum += __shfl_xor(ssum, 32);
    float ns = m + __logf(ssum) + logits[(size_t)(s*BB + b)*TT + tp];
    score = mask[b*SS + s] ? ns : score;
  }
  float v = score + endt[tp];
  float mm = v;
  for (int d = 1; d < 32; d <<= 1) mm = fmaxf(mm, __shfl_xor(mm, d));
  float se = __expf(v - mm);
  for (int d = 1; d < 32; d <<= 1) se += __shfl_xor(se, d);
  if (lane == 0) den[b] = mm + __logf(se);
}

// ---------------- CRF numerator, wave per batch ----------------
__global__ void k_num(const float* __restrict__ logits, const int* __restrict__ mask,
                      const int* __restrict__ labels,
                      const float* __restrict__ start, const float* __restrict__ endt,
                      const float* __restrict__ trans, float* __restrict__ num)
{
  int lane = threadIdx.x & 63, w = threadIdx.x >> 6;
  int b = blockIdx.x*4 + w;
  float acc = 0.f; int mcnt = 0;
  for (int s = lane; s < SS; s += 64){
    int mk = mask[b*SS + s];
    mcnt += mk;
    if (s >= 1){
      int tg = labels[b*SS + s], tp = labels[b*SS + s - 1];
      float v = trans[tp*32 + tg] + logits[(size_t)(s*BB + b)*TT + tg];
      acc += mk ? v : 0.f;
    }
  }
  for (int d = 1; d < 64; d <<= 1){ acc += __shfl_xor(acc, d); mcnt += __shfl_xor(mcnt, d); }
  if (lane == 0){
    int t0 = labels[b*SS];
    int tl = labels[b*SS + (mcnt - 1)];
    num[b] = start[t0] + logits[(size_t)b*TT + t0] + acc + endt[tl];
  }
}

// ---------------- Viterbi + backtrace, wave per batch; writes preds to d_out ----------------
__global__ void k_vit(const float* __restrict__ logits, const int* __restrict__ mask,
                      const float* __restrict__ start, const float* __restrict__ endt,
                      const float* __restrict__ trans,
                      unsigned char* __restrict__ vhist, float* __restrict__ preds)
{
  __shared__ float tr[1024];
  int tid = threadIdx.x;
  for (int i = tid; i < 1024; i += 256) tr[i] = trans[i];
  __syncthreads();
  int lane = tid & 63, w = tid >> 6;
  int b = blockIdx.x*4 + w;
  int grp = lane >> 5, tp = lane & 31;
  float score = start[tp] + logits[(size_t)b*TT + tp];
  for (int s = 1; s < SS; ++s){
    float m = -1e30f; int am = 0;
#pragma unroll
    for (int jj = 0; jj < 16; ++jj){
      int j = grp*16 + jj;
      float v = __shfl(score, j) + tr[j*32 + tp];
      if (v > m){ m = v; am = j; }
    }
    float om = __shfl_xor(m, 32); int oam = __shfl_xor(am, 32);
    if (om > m || (om == m && oam < am)){ m = om; am = oam; }
    int mk = mask[b*SS + s];
    float ns = m + logits[(size_t)(s*BB + b)*TT + tp];
    int idx = mk ? am : tp;
    if (grp == 0) vhist[(size_t)(s*BB + b)*32 + tp] = (unsigned char)idx;
    score = mk ? ns : score;
  }
  float v = score + endt[tp]; int a = tp;
  for (int d = 1; d < 32; d <<= 1){
    float ov = __shfl_xor(v, d); int oa = __shfl_xor(a, d);
    if (ov > v || (ov == v && oa < a)){ v = ov; a = oa; }
  }
  int tag = __shfl(a, 0);
  if (lane == 0) preds[(size_t)b*SS + SS - 1] = (float)tag;
  for (int s = SS - 1; s >= 1; --s){
    int rv = vhist[(size_t)(s*BB + b)*32 + tp];
    int pv = __shfl(rv, tag);
    if (lane == 0) preds[(size_t)b*SS + s - 1] = (float)pv;
    tag = pv;
  }
}

// ---------------- loss = -(sum_b num-den), written at d_out[B*S] ----------------
__global__ void k_loss(const float* __restrict__ num, const float* __restrict__ den,
                       float* __restrict__ out)
{
  int l = threadIdx.x;
  float v = num[l] - den[l];
  for (int d = 1; d < 64; d <<= 1) v += __shfl_xor(v, d);
  if (l == 0) out[BB*SS] = -v;
}

extern "C" void kernel_launch(void* const* d_in, const int* in_sizes, int n_in,
                              void* d_out, int out_size, void* d_ws, size_t ws_size,
                              hipStream_t stream)
{
  const int*   seq       = (const int*)  d_in[0];
  const int*   mask      = (const int*)  d_in[1];
  const int*   labels    = (const int*)  d_in[2];
  const float* embedding = (const float*)d_in[3];
  const float* Wih_f     = (const float*)d_in[4];
  const float* Whh_f     = (const float*)d_in[5];
  const float* bih_f     = (const float*)d_in[6];
  const float* bhh_f     = (const float*)d_in[7];
  const float* Wih_b     = (const float*)d_in[8];
  const float* Whh_b     = (const float*)d_in[9];
  const float* bih_b     = (const float*)d_in[10];
  const float* bhh_b     = (const float*)d_in[11];
  const float* fcW       = (const float*)d_in[12];
  const float* fcb       = (const float*)d_in[13];
  const float* start_t   = (const float*)d_in[14];
  const float* end_t     = (const float*)d_in[15];
  const float* trans     = (const float*)d_in[16];

  char* ws = (char*)d_ws;
  size_t off = 0;
  unsigned short* embq = (unsigned short*)(ws + off); off += (size_t)SS*BB*HH*2;        // 16 MiB
  unsigned short* hf   = (unsigned short*)(ws + off); off += (size_t)(SS+1)*BB*HH*2;    // 16 MiB
  unsigned short* hb   = (unsigned short*)(ws + off); off += (size_t)(SS+1)*BB*HH*2;    // 16 MiB
  float*          lgt  = (float*)(ws + off);          off += (size_t)SS*BB*TT*4;        // 4 MiB
  unsigned char*  vh   = (unsigned char*)(ws + off);  off += (size_t)SS*BB*TT;          // 1 MiB
  float*          den  = (float*)(ws + off);          off += 256;
  float*          num  = (float*)(ws + off);          off += 256;
  unsigned int*   cnt  = (unsigned int*)(ws + off);   off += 2*SS*4;

  // init: zero h boundary slots + step counters
  hipMemsetAsync(hf, 0, (size_t)BB*HH*2, stream);
  hipMemsetAsync(hb + (size_t)SS*BB*HH, 0, (size_t)BB*HH*2, stream);
  hipMemsetAsync(cnt, 0, 2*SS*4, stream);

  k_gather<<<4096, 256, 0, stream>>>(seq, embedding, embq);
  k_lstm<<<32, 256, 0, stream>>>(embq, Wih_f, Whh_f, bih_f, bhh_f,
                                 Wih_b, Whh_b, bih_b, bhh_b, hf, hb, cnt);
  k_fc<<<1024, 256, 0, stream>>>(hf, hb, fcW, fcb, lgt);
  k_den<<<16, 256, 0, stream>>>(lgt, mask, start_t, end_t, trans, den);
  k_num<<<16, 256, 0, stream>>>(lgt, mask, labels, start_t, end_t, trans, num);
  k_vit<<<16, 256, 0, stream>>>(lgt, mask, start_t, end_t, trans, vh, (float*)d_out);
  k_loss<<<1, 64, 0, stream>>>(num, den, (float*)d_out);
}

// Round 2
// 4876.472 us; speedup vs baseline: 1.0086x; 1.0086x over previous
//
#include <hip/hip_runtime.h>
#include <stdint.h>

#define SS 512
#define BB 64
#define HH 256
#define TT 32

typedef __attribute__((ext_vector_type(8))) short bf16x8;
typedef __attribute__((ext_vector_type(4))) short short4v;
typedef __attribute__((ext_vector_type(4))) float f32x4;

__device__ __forceinline__ unsigned short f2bf(float f){
  unsigned u = __float_as_uint(f);
  unsigned r = (u + 0x7FFFu + ((u >> 16) & 1u)) >> 16;
  return (unsigned short)r;
}
__device__ __forceinline__ float bf2f(unsigned short s){
  return __uint_as_float(((unsigned)s) << 16);
}
__device__ __forceinline__ float sigm(float x){ return 1.0f/(1.0f+__expf(-x)); }

// A/B fragment read from swizzled LDS tile [rows][256 cols] bf16.
// k-map applied identically to A and B, so any k-permutation cancels.
__device__ __forceinline__ bf16x8 afrag(const unsigned short* A, int mt, int ktp, int nl, int kq){
  int m = mt*16 + nl;
  int sw = (m & 7) << 3;
  int kk = ktp*32 + kq*4;
  short4v lo = *(const short4v*)(A + (m << 8) + (kk ^ sw));
  short4v hi = *(const short4v*)(A + (m << 8) + ((kk + 16) ^ sw));
  bf16x8 r = {lo[0],lo[1],lo[2],lo[3],hi[0],hi[1],hi[2],hi[3]};
  return r;
}

// ---------------- fused gather + x@Wih^T GEMM -> gx bf16 [2][32768][1024] ----------------
// grid (256, 2): (p-tile of 128 rows, dir). K=256 full. N looped in 64-col tiles.
__global__ __launch_bounds__(256,1) void k_xgemm(
    const int* __restrict__ seq, const float* __restrict__ emb,
    const float* __restrict__ Wih_f, const float* __restrict__ Wih_b,
    unsigned short* __restrict__ gx)
{
  __shared__ __align__(16) unsigned short A_l[128*256];  // 64 KiB
  __shared__ __align__(16) unsigned short B_l[64*256];   // 32 KiB

  const int tid = threadIdx.x;
  const int lane = tid & 63, w = tid >> 6;
  const int nl = lane & 15, kq = lane >> 4;
  const int pbase = blockIdx.x * 128;
  const int dir = blockIdx.y;
  const float* Wih = dir ? Wih_b : Wih_f;
  unsigned short* gxd = gx + (size_t)dir*32768*1024;

  // stage A: 128 rows (p = t*64+b), gather embedding rows, f32->bf16
#pragma unroll
  for (int i = 0; i < 16; ++i){
    int c = tid + i*256;               // granule = 8 bf16
    int m = c >> 5, k8 = c & 31;
    int p = pbase + m, t = p >> 6, b = p & 63;
    int er = seq[b*SS + t];
    const float* s = emb + (size_t)er*HH + k8*8;
    float4 x0 = *(const float4*)s, x1 = *(const float4*)(s+4);
    union { unsigned short u[8]; uint4 v; } o;
    o.u[0]=f2bf(x0.x); o.u[1]=f2bf(x0.y); o.u[2]=f2bf(x0.z); o.u[3]=f2bf(x0.w);
    o.u[4]=f2bf(x1.x); o.u[5]=f2bf(x1.y); o.u[6]=f2bf(x1.z); o.u[7]=f2bf(x1.w);
    *(uint4*)&A_l[(m << 8) + ((k8*8) ^ ((m & 7) << 3))] = o.v;
  }

  for (int nb = 0; nb < 16; ++nb){     // 16 x 64-col tiles
    __syncthreads();                   // prior MFMA reads of B_l done
#pragma unroll
    for (int i = 0; i < 8; ++i){
      int c = tid + i*256;
      int m = c >> 5, k8 = c & 31;     // m = col within tile
      const float* s = Wih + (size_t)(nb*64 + m)*HH + k8*8;
      float4 x0 = *(const float4*)s, x1 = *(const float4*)(s+4);
      union { unsigned short u[8]; uint4 v; } o;
      o.u[0]=f2bf(x0.x); o.u[1]=f2bf(x0.y); o.u[2]=f2bf(x0.z); o.u[3]=f2bf(x0.w);
      o.u[4]=f2bf(x1.x); o.u[5]=f2bf(x1.y); o.u[6]=f2bf(x1.z); o.u[7]=f2bf(x1.w);
      *(uint4*)&B_l[(m << 8) + ((k8*8) ^ ((m & 7) << 3))] = o.v;
    }
    __syncthreads();

    f32x4 acc[2][4];
#pragma unroll
    for (int mt = 0; mt < 2; ++mt)
#pragma unroll
      for (int nt = 0; nt < 4; ++nt) acc[mt][nt] = (f32x4){0.f,0.f,0.f,0.f};

#pragma unroll
    for (int kt = 0; kt < 8; ++kt){
      bf16x8 a0 = afrag(A_l, w*2+0, kt, nl, kq);
      bf16x8 a1 = afrag(A_l, w*2+1, kt, nl, kq);
#pragma unroll
      for (int nt = 0; nt < 4; ++nt){
        bf16x8 bv = afrag(B_l, nt, kt, nl, kq);
        acc[0][nt] = __builtin_amdgcn_mfma_f32_16x16x32_bf16(a0, bv, acc[0][nt], 0,0,0);
        acc[1][nt] = __builtin_amdgcn_mfma_f32_16x16x32_bf16(a1, bv, acc[1][nt], 0,0,0);
      }
    }

    // store: C row = pbase + w*32 + mt*16 + kq*4 + r ; col = nb*64 + nt*16 + nl
#pragma unroll
    for (int mt = 0; mt < 2; ++mt)
#pragma unroll
      for (int nt = 0; nt < 4; ++nt)
#pragma unroll
        for (int r = 0; r < 4; ++r){
          int row = pbase + w*32 + mt*16 + kq*4 + r;
          int col = nb*64 + nt*16 + nl;
          gxd[(size_t)row*1024 + col] = f2bf(acc[mt][nt][r]);
        }
  }
}

// ---------------- persistent bidirectional LSTM (h-recurrence only) ----------------
// 32 blocks: 16 fwd + 16 bwd. WG owns 16 h-cols; wave w computes gate w for them.
__global__ __launch_bounds__(256,1) void k_lstm(
    const unsigned short* __restrict__ gx,
    const float* __restrict__ Whh_f, const float* __restrict__ bih_f, const float* __restrict__ bhh_f,
    const float* __restrict__ Whh_b, const float* __restrict__ bih_b, const float* __restrict__ bhh_b,
    unsigned short* __restrict__ hf, unsigned short* __restrict__ hb,
    unsigned int* cnt)
{
  __shared__ __align__(16) unsigned short h_l[64*256];   // 32 KiB
  __shared__ __align__(16) float g_lds[4][64][20];       // 20.5 KiB

  const int tid  = threadIdx.x;
  const int lane = tid & 63;
  const int w    = tid >> 6;           // gate (i,f,g,o)
  const int dir  = blockIdx.x >> 4;
  const int wg   = blockIdx.x & 15;

  const float* Whh = dir ? Whh_b : Whh_f;
  const float* bih = dir ? bih_b : bih_f;
  const float* bhh = dir ? bhh_b : bhh_f;
  unsigned short* hbuf = dir ? hb : hf;
  const unsigned short* gxd = gx + (size_t)dir*32768*1024;
  unsigned int* mycnt = cnt + dir*SS;

  const int nl = lane & 15;
  const int kq = lane >> 4;
  const int ncol = w*256 + wg*16 + nl;   // global gate column

  // Whh B-fragments in VGPRs (32 regs/lane)
  bf16x8 wf[8];
#pragma unroll
  for (int kt = 0; kt < 8; ++kt){
    int k0 = kt*32 + kq*4;
    const float* p = Whh + (size_t)ncol*HH + k0;
    float4 lo = *(const float4*)p;
    float4 hi = *(const float4*)(p + 16);
    bf16x8 f;
    f[0]=(short)f2bf(lo.x); f[1]=(short)f2bf(lo.y); f[2]=(short)f2bf(lo.z); f[3]=(short)f2bf(lo.w);
    f[4]=(short)f2bf(hi.x); f[5]=(short)f2bf(hi.y); f[6]=(short)f2bf(hi.z); f[7]=(short)f2bf(hi.w);
    wf[kt] = f;
  }

  // combine-thread mapping: batch cb, h-cols wg*16 + cj..cj+3
  const int cb = tid >> 2;
  const int cj = (tid & 3) * 4;
  // per-gate bias for this thread's 4 h-cols (loop-invariant)
  float bias[4][4];
#pragma unroll
  for (int g = 0; g < 4; ++g)
#pragma unroll
    for (int jj = 0; jj < 4; ++jj){
      int col = g*256 + wg*16 + cj + jj;
      bias[g][jj] = bih[col] + bhh[col];
    }

  float c0=0.f, c1=0.f, c2=0.f, c3=0.f;

  for (int s = 0; s < SS; ++s){
    const int t = dir ? (SS-1-s) : s;

    // prefetch gx (independent of recurrence)
    uint2 gxv[4];
#pragma unroll
    for (int g = 0; g < 4; ++g)
      gxv[g] = *(const uint2*)(gxd + (size_t)(t*BB + cb)*1024 + g*256 + wg*16 + cj);

    if (s > 0){
      int guard = 0;
      while (__hip_atomic_load(mycnt + (s-1), __ATOMIC_RELAXED, __HIP_MEMORY_SCOPE_AGENT) < 16u){
        if (++guard > (1 << 22)) break;
      }
      __threadfence();   // acquire: one cache-maintenance per step, not per poll
    }

    { // stage h_prev (swizzled)
      const int rslot = dir ? (t + 1) : s;
      const unsigned short* src = hbuf + (size_t)rslot*BB*HH;
#pragma unroll
      for (int i = 0; i < 8; ++i){
        int c = tid + i*256; int m = c >> 5, k8 = c & 31;
        uint4 v = *(const uint4*)(src + m*HH + k8*8);
        *(uint4*)&h_l[(m << 8) + ((k8*8) ^ ((m & 7) << 3))] = v;
      }
    }
    __syncthreads();

    f32x4 acc0 = {0.f,0.f,0.f,0.f};
    f32x4 acc1 = acc0, acc2 = acc0, acc3 = acc0;
#pragma unroll
    for (int kt = 0; kt < 8; ++kt){
      bf16x8 wv = wf[kt];
      acc0 = __builtin_amdgcn_mfma_f32_16x16x32_bf16(afrag(h_l,0,kt,nl,kq), wv, acc0, 0,0,0);
      acc1 = __builtin_amdgcn_mfma_f32_16x16x32_bf16(afrag(h_l,1,kt,nl,kq), wv, acc1, 0,0,0);
      acc2 = __builtin_amdgcn_mfma_f32_16x16x32_bf16(afrag(h_l,2,kt,nl,kq), wv, acc2, 0,0,0);
      acc3 = __builtin_amdgcn_mfma_f32_16x16x32_bf16(afrag(h_l,3,kt,nl,kq), wv, acc3, 0,0,0);
    }

    { // publish gates: D map col=lane&15, row=(lane>>4)*4+reg
      int rb = kq*4;
#pragma unroll
      for (int r = 0; r < 4; ++r){
        g_lds[w][ 0 + rb + r][nl] = acc0[r];
        g_lds[w][16 + rb + r][nl] = acc1[r];
        g_lds[w][32 + rb + r][nl] = acc2[r];
        g_lds[w][48 + rb + r][nl] = acc3[r];
      }
    }
    __syncthreads();

    { // combine + c/h update
      f32x4 ig = *(const f32x4*)&g_lds[0][cb][cj];
      f32x4 fg = *(const f32x4*)&g_lds[1][cb][cj];
      f32x4 gg = *(const f32x4*)&g_lds[2][cb][cj];
      f32x4 og = *(const f32x4*)&g_lds[3][cb][cj];
      union { unsigned short u[4]; uint2 v; } hv;
      float cc, iv, fv, gv, ov;
#define STEP(J, CREG) \
      iv = ig[J] + bf2f(((unsigned short*)&gxv[0])[J]) + bias[0][J]; \
      fv = fg[J] + bf2f(((unsigned short*)&gxv[1])[J]) + bias[1][J]; \
      gv = gg[J] + bf2f(((unsigned short*)&gxv[2])[J]) + bias[2][J]; \
      ov = og[J] + bf2f(((unsigned short*)&gxv[3])[J]) + bias[3][J]; \
      cc = sigm(fv)*CREG + sigm(iv)*tanhf(gv); CREG = cc; \
      hv.u[J] = f2bf(sigm(ov)*tanhf(cc));
      STEP(0, c0) STEP(1, c1) STEP(2, c2) STEP(3, c3)
#undef STEP
      const int wslot = dir ? t : (s + 1);
      *(uint2*)(hbuf + (size_t)wslot*BB*HH + cb*HH + wg*16 + cj) = hv.v;
    }
    __syncthreads();   // drains stores (compiler emits vmcnt(0) before barrier)
    if (tid == 0){
      __threadfence();  // release
      __hip_atomic_fetch_add(mycnt + s, 1u, __ATOMIC_RELAXED, __HIP_MEMORY_SCOPE_AGENT);
    }
  }
}

// ---------------- FC via MFMA: logits[p][tag] = [hf(t+1);hb(t)] . fcW[tag] + fcb ----------------
__global__ __launch_bounds__(256,1) void k_fc(
    const unsigned short* __restrict__ hf, const unsigned short* __restrict__ hb,
    const float* __restrict__ fcW, const float* __restrict__ fcb,
    float* __restrict__ logits)
{
  __shared__ unsigned short Bs[32][520];
  __shared__ float fcb_s[32];
  const int tid = threadIdx.x;
  for (int i = tid; i < 32*512; i += 256){
    int tg = i >> 9, k = i & 511;
    Bs[tg][k] = f2bf(fcW[tg*512 + k]);
  }
  if (tid < 32) fcb_s[tid] = fcb[tid];
  __syncthreads();

  const int lane = tid & 63, w = tid >> 6;
  const int nl = lane & 15, kq = lane >> 4;
  const int pbase = blockIdx.x * 128;

  f32x4 acc[2][2];
#pragma unroll
  for (int mt = 0; mt < 2; ++mt)
#pragma unroll
    for (int nt = 0; nt < 2; ++nt) acc[mt][nt] = (f32x4){0.f,0.f,0.f,0.f};

#pragma unroll
  for (int kt = 0; kt < 16; ++kt){
    int k0 = kt*32 + kq*4;
    bf16x8 a[2];
#pragma unroll
    for (int mt = 0; mt < 2; ++mt){
      int p = pbase + w*32 + mt*16 + nl;
      int t = p >> 6, b = p & 63;
      const unsigned short* hr = (kt < 8)
        ? hf + (size_t)((t+1)*BB + b)*HH + k0
        : hb + (size_t)(t*BB + b)*HH + (k0 - 256);
      short4v lo = *(const short4v*)hr;
      short4v hi = *(const short4v*)(hr + 16);
      bf16x8 f = {lo[0],lo[1],lo[2],lo[3],hi[0],hi[1],hi[2],hi[3]};
      a[mt] = f;
    }
#pragma unroll
    for (int nt = 0; nt < 2; ++nt){
      const unsigned short* br = &Bs[nt*16 + nl][k0];
      short4v lo = *(const short4v*)br;
      short4v hi = *(const short4v*)(br + 16);
      bf16x8 bv = {lo[0],lo[1],lo[2],lo[3],hi[0],hi[1],hi[2],hi[3]};
      acc[0][nt] = __builtin_amdgcn_mfma_f32_16x16x32_bf16(a[0], bv, acc[0][nt], 0,0,0);
      acc[1][nt] = __builtin_amdgcn_mfma_f32_16x16x32_bf16(a[1], bv, acc[1][nt], 0,0,0);
    }
  }
#pragma unroll
  for (int mt = 0; mt < 2; ++mt)
#pragma unroll
    for (int nt = 0; nt < 2; ++nt)
#pragma unroll
      for (int r = 0; r < 4; ++r){
        int p = pbase + w*32 + mt*16 + kq*4 + r;
        int tg = nt*16 + nl;
        logits[(size_t)p*TT + tg] = acc[mt][nt][r] + fcb_s[tg];
      }
}

// ---------------- merged CRF: blocks 0-15 den, 16-31 vit, 32-47 num ----------------
__global__ void k_crf(const float* __restrict__ logits, const int* __restrict__ mask,
                      const int* __restrict__ labels,
                      const float* __restrict__ start, const float* __restrict__ endt,
                      const float* __restrict__ trans,
                      float* __restrict__ den, float* __restrict__ num,
                      unsigned char* __restrict__ vhist, float* __restrict__ preds)
{
  __shared__ float tr[1024];
  const int tid = threadIdx.x;
  const int role = blockIdx.x >> 4;
  const int bq   = blockIdx.x & 15;
  if (role != 2){
    for (int i = tid; i < 1024; i += 256) tr[i] = trans[i];
    __syncthreads();
  }
  const int lane = tid & 63, w = tid >> 6;
  const int b = bq*4 + w;
  const int grp = lane >> 5, tp = lane & 31;

  if (role == 0){ // denominator
    float score = start[tp] + logits[(size_t)b*TT + tp];
    for (int s = 1; s < SS; ++s){
      float m = -1e30f;
#pragma unroll
      for (int jj = 0; jj < 16; ++jj){
        int j = grp*16 + jj;
        float v = __shfl(score, j) + tr[j*32 + tp];
        m = fmaxf(m, v);
      }
      m = fmaxf(m, __shfl_xor(m, 32));
      float ssum = 0.f;
#pragma unroll
      for (int jj = 0; jj < 16; ++jj){
        int j = grp*16 + jj;
        float v = __shfl(score, j) + tr[j*32 + tp];
        ssum += __expf(v - m);
      }
      ssum += __shfl_xor(ssum, 32);
      float ns = m + __logf(ssum) + logits[(size_t)(s*BB + b)*TT + tp];
      score = mask[b*SS + s] ? ns : score;
    }
    float v = score + endt[tp];
    float mm = v;
    for (int d = 1; d < 32; d <<= 1) mm = fmaxf(mm, __shfl_xor(mm, d));
    float se = __expf(v - mm);
    for (int d = 1; d < 32; d <<= 1) se += __shfl_xor(se, d);
    if (lane == 0) den[b] = mm + __logf(se);
  } else if (role == 1){ // viterbi
    float score = start[tp] + logits[(size_t)b*TT + tp];
    for (int s = 1; s < SS; ++s){
      float m = -1e30f; int am = 0;
#pragma unroll
      for (int jj = 0; jj < 16; ++jj){
        int j = grp*16 + jj;
        float v = __shfl(score, j) + tr[j*32 + tp];
        if (v > m){ m = v; am = j; }
      }
      float om = __shfl_xor(m, 32); int oam = __shfl_xor(am, 32);
      if (om > m || (om == m && oam < am)){ m = om; am = oam; }
      int mk = mask[b*SS + s];
      float ns = m + logits[(size_t)(s*BB + b)*TT + tp];
      int idx = mk ? am : tp;
      if (grp == 0) vhist[(size_t)(s*BB + b)*32 + tp] = (unsigned char)idx;
      score = mk ? ns : score;
    }
    float v = score + endt[tp]; int a = tp;
    for (int d = 1; d < 32; d <<= 1){
      float ov = __shfl_xor(v, d); int oa = __shfl_xor(a, d);
      if (ov > v || (ov == v && oa < a)){ v = ov; a = oa; }
    }
    int tag = __shfl(a, 0);
    if (lane == 0) preds[(size_t)b*SS + SS - 1] = (float)tag;
    for (int s = SS - 1; s >= 1; --s){
      int rv = vhist[(size_t)(s*BB + b)*32 + tp];
      int pv = __shfl(rv, tag);
      if (lane == 0) preds[(size_t)b*SS + s - 1] = (float)pv;
      tag = pv;
    }
  } else { // numerator
    float acc = 0.f; int mcnt = 0;
    for (int s = lane; s < SS; s += 64){
      int mk = mask[b*SS + s];
      mcnt += mk;
      if (s >= 1){
        int tg = labels[b*SS + s], tpp = labels[b*SS + s - 1];
        float v = trans[tpp*32 + tg] + logits[(size_t)(s*BB + b)*TT + tg];
        acc += mk ? v : 0.f;
      }
    }
    for (int d = 1; d < 64; d <<= 1){ acc += __shfl_xor(acc, d); mcnt += __shfl_xor(mcnt, d); }
    if (lane == 0){
      int t0 = labels[b*SS];
      int tl = labels[b*SS + (mcnt - 1)];
      num[b] = start[t0] + logits[(size_t)b*TT + t0] + acc + endt[tl];
    }
  }
}

// ---------------- loss ----------------
__global__ void k_loss(const float* __restrict__ num, const float* __restrict__ den,
                       float* __restrict__ out)
{
  int l = threadIdx.x;
  float v = num[l] - den[l];
  for (int d = 1; d < 64; d <<= 1) v += __shfl_xor(v, d);
  if (l == 0) out[BB*SS] = -v;
}

extern "C" void kernel_launch(void* const* d_in, const int* in_sizes, int n_in,
                              void* d_out, int out_size, void* d_ws, size_t ws_size,
                              hipStream_t stream)
{
  const int*   seq       = (const int*)  d_in[0];
  const int*   mask      = (const int*)  d_in[1];
  const int*   labels    = (const int*)  d_in[2];
  const float* embedding = (const float*)d_in[3];
  const float* Wih_f     = (const float*)d_in[4];
  const float* Whh_f     = (const float*)d_in[5];
  const float* bih_f     = (const float*)d_in[6];
  const float* bhh_f     = (const float*)d_in[7];
  const float* Wih_b     = (const float*)d_in[8];
  const float* Whh_b     = (const float*)d_in[9];
  const float* bih_b     = (const float*)d_in[10];
  const float* bhh_b     = (const float*)d_in[11];
  const float* fcW       = (const float*)d_in[12];
  const float* fcb       = (const float*)d_in[13];
  const float* start_t   = (const float*)d_in[14];
  const float* end_t     = (const float*)d_in[15];
  const float* trans     = (const float*)d_in[16];

  char* ws = (char*)d_ws;
  size_t off = 0;
  unsigned short* gxb = (unsigned short*)(ws + off); off += (size_t)2*32768*1024*2;     // 128 MiB
  unsigned short* hf  = (unsigned short*)(ws + off); off += (size_t)(SS+1)*BB*HH*2;     // 16 MiB
  unsigned short* hb  = (unsigned short*)(ws + off); off += (size_t)(SS+1)*BB*HH*2;     // 16 MiB
  float*          lgt = (float*)(ws + off);          off += (size_t)SS*BB*TT*4;         // 4 MiB
  unsigned char*  vh  = (unsigned char*)(ws + off);  off += (size_t)SS*BB*TT;           // 1 MiB
  float*          den = (float*)(ws + off);          off += 256;
  float*          num = (float*)(ws + off);          off += 256;
  unsigned int*   cnt = (unsigned int*)(ws + off);   off += 2*SS*4;

  hipMemsetAsync(hf, 0, (size_t)BB*HH*2, stream);
  hipMemsetAsync(hb + (size_t)SS*BB*HH, 0, (size_t)BB*HH*2, stream);
  hipMemsetAsync(cnt, 0, 2*SS*4, stream);

  k_xgemm<<<dim3(256,2), 256, 0, stream>>>(seq, embedding, Wih_f, Wih_b, gxb);
  k_lstm<<<32, 256, 0, stream>>>(gxb, Whh_f, bih_f, bhh_f, Whh_b, bih_b, bhh_b, hf, hb, cnt);
  k_fc<<<256, 256, 0, stream>>>(hf, hb, fcW, fcb, lgt);
  k_crf<<<48, 256, 0, stream>>>(lgt, mask, labels, start_t, end_t, trans, den, num, vh, (float*)d_out);
  k_loss<<<1, 64, 0, stream>>>(num, den, (float*)d_out);
}

// Round 3
// 3570.054 us; speedup vs baseline: 1.3777x; 1.3659x over previous
//
#include <hip/hip_runtime.h>
#include <stdint.h>

#define SS 512
#define BB 64
#define HH 256
#define TT 32

typedef __attribute__((ext_vector_type(8))) short bf16x8;
typedef __attribute__((ext_vector_type(4))) short short4v;
typedef __attribute__((ext_vector_type(4))) float f32x4;

__device__ __forceinline__ unsigned short f2bf(float f){
  unsigned u = __float_as_uint(f);
  unsigned r = (u + 0x7FFFu + ((u >> 16) & 1u)) >> 16;
  return (unsigned short)r;
}
__device__ __forceinline__ float bf2f(unsigned short s){
  return __uint_as_float(((unsigned)s) << 16);
}
__device__ __forceinline__ float sigm(float x){ return 1.0f/(1.0f+__expf(-x)); }
__device__ __forceinline__ float ftanh(float x){
  float e = __expf(2.f*x);
  return 1.f - 2.f/(e + 1.f);
}

// swizzled-LDS fragment read (used by k_xgemm only)
__device__ __forceinline__ bf16x8 afrag(const unsigned short* A, int mt, int ktp, int nl, int kq){
  int m = mt*16 + nl;
  int sw = (m & 7) << 3;
  int kk = ktp*32 + kq*4;
  short4v lo = *(const short4v*)(A + (m << 8) + (kk ^ sw));
  short4v hi = *(const short4v*)(A + (m << 8) + ((kk + 16) ^ sw));
  bf16x8 r = {lo[0],lo[1],lo[2],lo[3],hi[0],hi[1],hi[2],hi[3]};
  return r;
}

// ---------------- fused gather + x@Wih^T GEMM -> gx bf16 [dir][t][col(1024)][b(64)] ----------------
__global__ __launch_bounds__(256,1) void k_xgemm(
    const int* __restrict__ seq, const float* __restrict__ emb,
    const float* __restrict__ Wih_f, const float* __restrict__ Wih_b,
    unsigned short* __restrict__ gx)
{
  __shared__ __align__(16) unsigned short A_l[128*256];  // 64 KiB
  __shared__ __align__(16) unsigned short B_l[64*256];   // 32 KiB

  const int tid = threadIdx.x;
  const int lane = tid & 63, w = tid >> 6;
  const int nl = lane & 15, kq = lane >> 4;
  const int pbase = blockIdx.x * 128;
  const int dir = blockIdx.y;
  const float* Wih = dir ? Wih_b : Wih_f;
  unsigned short* gxd = gx + (size_t)dir*SS*1024*64;

  // stage A: 128 rows (p = t*64+b), gather embedding rows, f32->bf16
#pragma unroll
  for (int i = 0; i < 16; ++i){
    int c = tid + i*256;
    int m = c >> 5, k8 = c & 31;
    int p = pbase + m, t = p >> 6, b = p & 63;
    int er = seq[b*SS + t];
    const float* s = emb + (size_t)er*HH + k8*8;
    float4 x0 = *(const float4*)s, x1 = *(const float4*)(s+4);
    union { unsigned short u[8]; uint4 v; } o;
    o.u[0]=f2bf(x0.x); o.u[1]=f2bf(x0.y); o.u[2]=f2bf(x0.z); o.u[3]=f2bf(x0.w);
    o.u[4]=f2bf(x1.x); o.u[5]=f2bf(x1.y); o.u[6]=f2bf(x1.z); o.u[7]=f2bf(x1.w);
    *(uint4*)&A_l[(m << 8) + ((k8*8) ^ ((m & 7) << 3))] = o.v;
  }

  for (int nb = 0; nb < 16; ++nb){
    __syncthreads();
#pragma unroll
    for (int i = 0; i < 8; ++i){
      int c = tid + i*256;
      int m = c >> 5, k8 = c & 31;     // m = col within tile
      const float* s = Wih + (size_t)(nb*64 + m)*HH + k8*8;
      float4 x0 = *(const float4*)s, x1 = *(const float4*)(s+4);
      union { unsigned short u[8]; uint4 v; } o;
      o.u[0]=f2bf(x0.x); o.u[1]=f2bf(x0.y); o.u[2]=f2bf(x0.z); o.u[3]=f2bf(x0.w);
      o.u[4]=f2bf(x1.x); o.u[5]=f2bf(x1.y); o.u[6]=f2bf(x1.z); o.u[7]=f2bf(x1.w);
      *(uint4*)&B_l[(m << 8) + ((k8*8) ^ ((m & 7) << 3))] = o.v;
    }
    __syncthreads();

    f32x4 acc[2][4];
#pragma unroll
    for (int mt = 0; mt < 2; ++mt)
#pragma unroll
      for (int nt = 0; nt < 4; ++nt) acc[mt][nt] = (f32x4){0.f,0.f,0.f,0.f};

#pragma unroll
    for (int kt = 0; kt < 8; ++kt){
      bf16x8 a0 = afrag(A_l, w*2+0, kt, nl, kq);
      bf16x8 a1 = afrag(A_l, w*2+1, kt, nl, kq);
#pragma unroll
      for (int nt = 0; nt < 4; ++nt){
        bf16x8 bv = afrag(B_l, nt, kt, nl, kq);
        acc[0][nt] = __builtin_amdgcn_mfma_f32_16x16x32_bf16(a0, bv, acc[0][nt], 0,0,0);
        acc[1][nt] = __builtin_amdgcn_mfma_f32_16x16x32_bf16(a1, bv, acc[1][nt], 0,0,0);
      }
    }

    // store to [t][col][b]: rows r=0..3 are consecutive b
#pragma unroll
    for (int mt = 0; mt < 2; ++mt)
#pragma unroll
      for (int nt = 0; nt < 4; ++nt){
        int p0 = pbase + w*32 + mt*16 + kq*4;
        int t = p0 >> 6, b0 = p0 & 63;
        int col = nb*64 + nt*16 + nl;
        union { unsigned short u[4]; uint2 v; } o;
        o.u[0]=f2bf(acc[mt][nt][0]); o.u[1]=f2bf(acc[mt][nt][1]);
        o.u[2]=f2bf(acc[mt][nt][2]); o.u[3]=f2bf(acc[mt][nt][3]);
        *(uint2*)(gxd + ((size_t)t*1024 + col)*64 + b0) = o.v;
      }
  }
}

// ---------------- persistent bidirectional LSTM, barrier-free, MALL-coherent exchange ----------------
// 32 blocks: 16 fwd + 16 bwd. WG wg owns h-cols wg*16..+15. Wave w owns batch rows w*16..+15
// and computes ALL 4 gates for them (gate combine is lane-local, no cross-wave exchange).
__global__ __launch_bounds__(256,1) void k_lstm(
    const unsigned short* __restrict__ gx,
    const float* __restrict__ Whh_f, const float* __restrict__ bih_f, const float* __restrict__ bhh_f,
    const float* __restrict__ Whh_b, const float* __restrict__ bih_b, const float* __restrict__ bhh_b,
    unsigned short* __restrict__ hf, unsigned short* __restrict__ hb,
    unsigned int* cnt)
{
  __shared__ unsigned short hstage[4][16][16];   // per-wave 16x16 transpose tile

  const int tid  = threadIdx.x;
  const int lane = tid & 63;
  const int w    = tid >> 6;           // wave: batch rows w*16..+15
  const int dir  = blockIdx.x >> 4;
  const int wg   = blockIdx.x & 15;
  const int nl   = lane & 15;
  const int kq   = lane >> 4;

  const float* Whh = dir ? Whh_b : Whh_f;
  const float* bih = dir ? bih_b : bih_f;
  const float* bhh = dir ? bhh_b : bhh_f;
  unsigned short* hbuf = dir ? hb : hf;
  const unsigned short* gxd = gx + (size_t)dir*SS*1024*64;
  unsigned int* mycnt = cnt + dir*SS*4;

  // B-fragments: wf[nt][kt], gate col = nt*256 + wg*16 + nl  (128 VGPRs)
  bf16x8 wf[4][8];
#pragma unroll
  for (int nt = 0; nt < 4; ++nt)
#pragma unroll
    for (int kt = 0; kt < 8; ++kt){
      const float* p = Whh + (size_t)(nt*256 + wg*16 + nl)*HH + kt*32 + kq*4;
      float4 lo = *(const float4*)p;
      float4 hi = *(const float4*)(p + 16);
      bf16x8 f;
      f[0]=(short)f2bf(lo.x); f[1]=(short)f2bf(lo.y); f[2]=(short)f2bf(lo.z); f[3]=(short)f2bf(lo.w);
      f[4]=(short)f2bf(hi.x); f[5]=(short)f2bf(hi.y); f[6]=(short)f2bf(hi.z); f[7]=(short)f2bf(hi.w);
      wf[nt][kt] = f;
    }

  float bias[4];
#pragma unroll
  for (int g = 0; g < 4; ++g){
    int col = g*256 + wg*16 + nl;
    bias[g] = bih[col] + bhh[col];
  }

  float c[4] = {0.f,0.f,0.f,0.f};   // batches w*16+kq*4+r, col wg*16+nl

  for (int s = 0; s < SS; ++s){
    const int t = dir ? (SS-1-s) : s;

    // gx prefetch (plain cached loads; independent of recurrence)
    union { uint2 v; unsigned short u[4]; } gxu[4];
#pragma unroll
    for (int g = 0; g < 4; ++g)
      gxu[g].v = *(const uint2*)(gxd + ((size_t)t*1024 + g*256 + wg*16 + nl)*64 + w*16 + kq*4);

    // wait for the 16 wave-class-w producers of step s-1 (relaxed MALL poll, no cache fences)
    if (s > 0){
      int guard = 0;
      while (__hip_atomic_load(&mycnt[(s-1)*4 + w], __ATOMIC_RELAXED, __HIP_MEMORY_SCOPE_AGENT) < 16u){
        if (++guard > (1 << 22)) break;
      }
      asm volatile("" ::: "memory");
    }

    // h_prev A-fragments: row = w*16+nl, direct global->VGPR via sc-flagged loads
    const int rslot = dir ? (t + 1) : s;
    const unsigned long long* hr =
      (const unsigned long long*)(hbuf + (size_t)rslot*BB*HH + (size_t)(w*16 + nl)*HH);
    bf16x8 af[8];
#pragma unroll
    for (int kt = 0; kt < 8; ++kt){
      unsigned long long lo = __hip_atomic_load(hr + kt*8 + kq,     __ATOMIC_RELAXED, __HIP_MEMORY_SCOPE_AGENT);
      unsigned long long hi = __hip_atomic_load(hr + kt*8 + kq + 4, __ATOMIC_RELAXED, __HIP_MEMORY_SCOPE_AGENT);
      union { unsigned long long u; short4v s4; } L, H;
      L.u = lo; H.u = hi;
      bf16x8 f = {L.s4[0],L.s4[1],L.s4[2],L.s4[3],H.s4[0],H.s4[1],H.s4[2],H.s4[3]};
      af[kt] = f;
    }

    f32x4 acc[4];
#pragma unroll
    for (int nt = 0; nt < 4; ++nt) acc[nt] = (f32x4){0.f,0.f,0.f,0.f};
#pragma unroll
    for (int kt = 0; kt < 8; ++kt)
#pragma unroll
      for (int nt = 0; nt < 4; ++nt)
        acc[nt] = __builtin_amdgcn_mfma_f32_16x16x32_bf16(af[kt], wf[nt][kt], acc[nt], 0,0,0);

    // lane-local gate combine: D lane(nl,kq) reg r -> batch w*16+kq*4+r, col wg*16+nl
#pragma unroll
    for (int r = 0; r < 4; ++r){
      float iv = acc[0][r] + bf2f(gxu[0].u[r]) + bias[0];
      float fv = acc[1][r] + bf2f(gxu[1].u[r]) + bias[1];
      float gv = acc[2][r] + bf2f(gxu[2].u[r]) + bias[2];
      float ov = acc[3][r] + bf2f(gxu[3].u[r]) + bias[3];
      float cc = sigm(fv)*c[r] + sigm(iv)*ftanh(gv);
      c[r] = cc;
      hstage[w][kq*4 + r][nl] = f2bf(sigm(ov)*ftanh(cc));
    }

    // same-wave 16x16 transpose through LDS -> one 8B coherent store per lane
    unsigned long long hv = *(const unsigned long long*)&hstage[w][lane & 15][(lane >> 4)*4];
    const int wslot = dir ? t : (s + 1);
    unsigned long long* dst =
      (unsigned long long*)(hbuf + (size_t)wslot*BB*HH + (size_t)(w*16 + (lane & 15))*HH + wg*16 + (lane >> 4)*4);
    __hip_atomic_store(dst, hv, __ATOMIC_RELAXED, __HIP_MEMORY_SCOPE_AGENT);

    asm volatile("s_waitcnt vmcnt(0)" ::: "memory");   // h stores complete at MALL
    if (lane == 0)
      __hip_atomic_fetch_add(&mycnt[s*4 + w], 1u, __ATOMIC_RELAXED, __HIP_MEMORY_SCOPE_AGENT);
  }
}

// ---------------- FC via MFMA: logits[p][tag] = [hf(t+1);hb(t)] . fcW[tag] + fcb ----------------
__global__ __launch_bounds__(256,1) void k_fc(
    const unsigned short* __restrict__ hf, const unsigned short* __restrict__ hb,
    const float* __restrict__ fcW, const float* __restrict__ fcb,
    float* __restrict__ logits)
{
  __shared__ unsigned short Bs[32][520];
  __shared__ float fcb_s[32];
  const int tid = threadIdx.x;
  for (int i = tid; i < 32*512; i += 256){
    int tg = i >> 9, k = i & 511;
    Bs[tg][k] = f2bf(fcW[tg*512 + k]);
  }
  if (tid < 32) fcb_s[tid] = fcb[tid];
  __syncthreads();

  const int lane = tid & 63, w = tid >> 6;
  const int nl = lane & 15, kq = lane >> 4;
  const int pbase = blockIdx.x * 128;

  f32x4 acc[2][2];
#pragma unroll
  for (int mt = 0; mt < 2; ++mt)
#pragma unroll
    for (int nt = 0; nt < 2; ++nt) acc[mt][nt] = (f32x4){0.f,0.f,0.f,0.f};

#pragma unroll
  for (int kt = 0; kt < 16; ++kt){
    int k0 = kt*32 + kq*4;
    bf16x8 a[2];
#pragma unroll
    for (int mt = 0; mt < 2; ++mt){
      int p = pbase + w*32 + mt*16 + nl;
      int t = p >> 6, b = p & 63;
      const unsigned short* hrp = (kt < 8)
        ? hf + (size_t)((t+1)*BB + b)*HH + k0
        : hb + (size_t)(t*BB + b)*HH + (k0 - 256);
      short4v lo = *(const short4v*)hrp;
      short4v hi = *(const short4v*)(hrp + 16);
      bf16x8 f = {lo[0],lo[1],lo[2],lo[3],hi[0],hi[1],hi[2],hi[3]};
      a[mt] = f;
    }
#pragma unroll
    for (int nt = 0; nt < 2; ++nt){
      const unsigned short* br = &Bs[nt*16 + nl][k0];
      short4v lo = *(const short4v*)br;
      short4v hi = *(const short4v*)(br + 16);
      bf16x8 bv = {lo[0],lo[1],lo[2],lo[3],hi[0],hi[1],hi[2],hi[3]};
      acc[0][nt] = __builtin_amdgcn_mfma_f32_16x16x32_bf16(a[0], bv, acc[0][nt], 0,0,0);
      acc[1][nt] = __builtin_amdgcn_mfma_f32_16x16x32_bf16(a[1], bv, acc[1][nt], 0,0,0);
    }
  }
#pragma unroll
  for (int mt = 0; mt < 2; ++mt)
#pragma unroll
    for (int nt = 0; nt < 2; ++nt)
#pragma unroll
      for (int r = 0; r < 4; ++r){
        int p = pbase + w*32 + mt*16 + kq*4 + r;
        int tg = nt*16 + nl;
        logits[(size_t)p*TT + tg] = acc[mt][nt][r] + fcb_s[tg];
      }
}

// ---------------- merged CRF: blocks 0-15 den, 16-31 vit, 32-47 num ----------------
__global__ void k_crf(const float* __restrict__ logits, const int* __restrict__ mask,
                      const int* __restrict__ labels,
                      const float* __restrict__ start, const float* __restrict__ endt,
                      const float* __restrict__ trans,
                      float* __restrict__ den, float* __restrict__ num,
                      unsigned char* __restrict__ vhist, float* __restrict__ preds)
{
  __shared__ float tr[1024];
  const int tid = threadIdx.x;
  const int role = blockIdx.x >> 4;
  const int bq   = blockIdx.x & 15;
  if (role != 2){
    for (int i = tid; i < 1024; i += 256) tr[i] = trans[i];
    __syncthreads();
  }
  const int lane = tid & 63, w = tid >> 6;
  const int b = bq*4 + w;
  const int grp = lane >> 5, tp = lane & 31;

  if (role == 0){ // denominator
    float score = start[tp] + logits[(size_t)b*TT + tp];
    for (int s = 1; s < SS; ++s){
      float m = -1e30f;
#pragma unroll
      for (int jj = 0; jj < 16; ++jj){
        int j = grp*16 + jj;
        float v = __shfl(score, j) + tr[j*32 + tp];
        m = fmaxf(m, v);
      }
      m = fmaxf(m, __shfl_xor(m, 32));
      float ssum = 0.f;
#pragma unroll
      for (int jj = 0; jj < 16; ++jj){
        int j = grp*16 + jj;
        float v = __shfl(score, j) + tr[j*32 + tp];
        ssum += __expf(v - m);
      }
      ssum += __shfl_xor(ssum, 32);
      float ns = m + __logf(ssum) + logits[(size_t)(s*BB + b)*TT + tp];
      score = mask[b*SS + s] ? ns : score;
    }
    float v = score + endt[tp];
    float mm = v;
    for (int d = 1; d < 32; d <<= 1) mm = fmaxf(mm, __shfl_xor(mm, d));
    float se = __expf(v - mm);
    for (int d = 1; d < 32; d <<= 1) se += __shfl_xor(se, d);
    if (lane == 0) den[b] = mm + __logf(se);
  } else if (role == 1){ // viterbi
    float score = start[tp] + logits[(size_t)b*TT + tp];
    for (int s = 1; s < SS; ++s){
      float m = -1e30f; int am = 0;
#pragma unroll
      for (int jj = 0; jj < 16; ++jj){
        int j = grp*16 + jj;
        float v = __shfl(score, j) + tr[j*32 + tp];
        if (v > m){ m = v; am = j; }
      }
      float om = __shfl_xor(m, 32); int oam = __shfl_xor(am, 32);
      if (om > m || (om == m && oam < am)){ m = om; am = oam; }
      int mk = mask[b*SS + s];
      float ns = m + logits[(size_t)(s*BB + b)*TT + tp];
      int idx = mk ? am : tp;
      if (grp == 0) vhist[(size_t)(s*BB + b)*32 + tp] = (unsigned char)idx;
      score = mk ? ns : score;
    }
    float v = score + endt[tp]; int a = tp;
    for (int d = 1; d < 32; d <<= 1){
      float ov = __shfl_xor(v, d); int oa = __shfl_xor(a, d);
      if (ov > v || (ov == v && oa < a)){ v = ov; a = oa; }
    }
    int tag = __shfl(a, 0);
    if (lane == 0) preds[(size_t)b*SS + SS - 1] = (float)tag;
    for (int s = SS - 1; s >= 1; --s){
      int rv = vhist[(size_t)(s*BB + b)*32 + tp];
      int pv = __shfl(rv, tag);
      if (lane == 0) preds[(size_t)b*SS + s - 1] = (float)pv;
      tag = pv;
    }
  } else { // numerator
    float acc = 0.f; int mcnt = 0;
    for (int s = lane; s < SS; s += 64){
      int mk = mask[b*SS + s];
      mcnt += mk;
      if (s >= 1){
        int tg = labels[b*SS + s], tpp = labels[b*SS + s - 1];
        float v = trans[tpp*32 + tg] + logits[(size_t)(s*BB + b)*TT + tg];
        acc += mk ? v : 0.f;
      }
    }
    for (int d = 1; d < 64; d <<= 1){ acc += __shfl_xor(acc, d); mcnt += __shfl_xor(mcnt, d); }
    if (lane == 0){
      int t0 = labels[b*SS];
      int tl = labels[b*SS + (mcnt - 1)];
      num[b] = start[t0] + logits[(size_t)b*TT + t0] + acc + endt[tl];
    }
  }
}

// ---------------- loss ----------------
__global__ void k_loss(const float* __restrict__ num, const float* __restrict__ den,
                       float* __restrict__ out)
{
  int l = threadIdx.x;
  float v = num[l] - den[l];
  for (int d = 1; d < 64; d <<= 1) v += __shfl_xor(v, d);
  if (l == 0) out[BB*SS] = -v;
}

extern "C" void kernel_launch(void* const* d_in, const int* in_sizes, int n_in,
                              void* d_out, int out_size, void* d_ws, size_t ws_size,
                              hipStream_t stream)
{
  const int*   seq       = (const int*)  d_in[0];
  const int*   mask      = (const int*)  d_in[1];
  const int*   labels    = (const int*)  d_in[2];
  const float* embedding = (const float*)d_in[3];
  const float* Wih_f     = (const float*)d_in[4];
  const float* Whh_f     = (const float*)d_in[5];
  const float* bih_f     = (const float*)d_in[6];
  const float* bhh_f     = (const float*)d_in[7];
  const float* Wih_b     = (const float*)d_in[8];
  const float* Whh_b     = (const float*)d_in[9];
  const float* bih_b     = (const float*)d_in[10];
  const float* bhh_b     = (const float*)d_in[11];
  const float* fcW       = (const float*)d_in[12];
  const float* fcb       = (const float*)d_in[13];
  const float* start_t   = (const float*)d_in[14];
  const float* end_t     = (const float*)d_in[15];
  const float* trans     = (const float*)d_in[16];

  char* ws = (char*)d_ws;
  size_t off = 0;
  unsigned short* gxb = (unsigned short*)(ws + off); off += (size_t)2*SS*1024*64*2;     // 128 MiB
  unsigned short* hf  = (unsigned short*)(ws + off); off += (size_t)(SS+1)*BB*HH*2;     // 16 MiB
  unsigned short* hb  = (unsigned short*)(ws + off); off += (size_t)(SS+1)*BB*HH*2;     // 16 MiB
  float*          lgt = (float*)(ws + off);          off += (size_t)SS*BB*TT*4;         // 4 MiB
  unsigned char*  vh  = (unsigned char*)(ws + off);  off += (size_t)SS*BB*TT;           // 1 MiB
  float*          den = (float*)(ws + off);          off += 256;
  float*          num = (float*)(ws + off);          off += 256;
  unsigned int*   cnt = (unsigned int*)(ws + off);   off += 2*SS*4*4;

  hipMemsetAsync(hf, 0, (size_t)BB*HH*2, stream);
  hipMemsetAsync(hb + (size_t)SS*BB*HH, 0, (size_t)BB*HH*2, stream);
  hipMemsetAsync(cnt, 0, 2*SS*4*4, stream);

  k_xgemm<<<dim3(256,2), 256, 0, stream>>>(seq, embedding, Wih_f, Wih_b, gxb);
  k_lstm<<<32, 256, 0, stream>>>(gxb, Whh_f, bih_f, bhh_f, Whh_b, bih_b, bhh_b, hf, hb, cnt);
  k_fc<<<256, 256, 0, stream>>>(hf, hb, fcW, fcb, lgt);
  k_crf<<<48, 256, 0, stream>>>(lgt, mask, labels, start_t, end_t, trans, den, num, vh, (float*)d_out);
  k_loss<<<1, 64, 0, stream>>>(num, den, (float*)d_out);
}

// Round 4
// 3139.740 us; speedup vs baseline: 1.5666x; 1.1371x over previous
//
#include <hip/hip_runtime.h>
#include <stdint.h>

#define SS 512
#define BB 64
#define HH 256
#define TT 32

typedef __attribute__((ext_vector_type(8))) short bf16x8;
typedef __attribute__((ext_vector_type(4))) short short4v;
typedef __attribute__((ext_vector_type(4))) float f32x4;

__device__ __forceinline__ unsigned short f2bf(float f){
  unsigned u = __float_as_uint(f);
  unsigned r = (u + 0x7FFFu + ((u >> 16) & 1u)) >> 16;
  return (unsigned short)r;
}
__device__ __forceinline__ float bf2f(unsigned short s){
  return __uint_as_float(((unsigned)s) << 16);
}
__device__ __forceinline__ float sigm(float x){ return 1.0f/(1.0f+__expf(-x)); }
__device__ __forceinline__ float ftanh(float x){
  float e = __expf(2.f*x);
  return 1.f - 2.f/(e + 1.f);
}

// swizzled-LDS fragment read (used by k_xgemm only)
__device__ __forceinline__ bf16x8 afrag(const unsigned short* A, int mt, int ktp, int nl, int kq){
  int m = mt*16 + nl;
  int sw = (m & 7) << 3;
  int kk = ktp*32 + kq*4;
  short4v lo = *(const short4v*)(A + (m << 8) + (kk ^ sw));
  short4v hi = *(const short4v*)(A + (m << 8) + ((kk + 16) ^ sw));
  bf16x8 r = {lo[0],lo[1],lo[2],lo[3],hi[0],hi[1],hi[2],hi[3]};
  return r;
}

// ---------------- fused gather + x@Wih^T GEMM -> gx bf16 [dir][t][col(1024)][b(64)] ----------------
__global__ __launch_bounds__(256,1) void k_xgemm(
    const int* __restrict__ seq, const float* __restrict__ emb,
    const float* __restrict__ Wih_f, const float* __restrict__ Wih_b,
    unsigned short* __restrict__ gx)
{
  __shared__ __align__(16) unsigned short A_l[128*256];  // 64 KiB
  __shared__ __align__(16) unsigned short B_l[64*256];   // 32 KiB

  const int tid = threadIdx.x;
  const int lane = tid & 63, w = tid >> 6;
  const int nl = lane & 15, kq = lane >> 4;
  const int pbase = blockIdx.x * 128;
  const int dir = blockIdx.y;
  const float* Wih = dir ? Wih_b : Wih_f;
  unsigned short* gxd = gx + (size_t)dir*SS*1024*64;

  // stage A: 128 rows (p = t*64+b), gather embedding rows, f32->bf16
#pragma unroll
  for (int i = 0; i < 16; ++i){
    int c = tid + i*256;
    int m = c >> 5, k8 = c & 31;
    int p = pbase + m, t = p >> 6, b = p & 63;
    int er = seq[b*SS + t];
    const float* s = emb + (size_t)er*HH + k8*8;
    float4 x0 = *(const float4*)s, x1 = *(const float4*)(s+4);
    union { unsigned short u[8]; uint4 v; } o;
    o.u[0]=f2bf(x0.x); o.u[1]=f2bf(x0.y); o.u[2]=f2bf(x0.z); o.u[3]=f2bf(x0.w);
    o.u[4]=f2bf(x1.x); o.u[5]=f2bf(x1.y); o.u[6]=f2bf(x1.z); o.u[7]=f2bf(x1.w);
    *(uint4*)&A_l[(m << 8) + ((k8*8) ^ ((m & 7) << 3))] = o.v;
  }

  for (int nb = 0; nb < 16; ++nb){
    __syncthreads();
#pragma unroll
    for (int i = 0; i < 8; ++i){
      int c = tid + i*256;
      int m = c >> 5, k8 = c & 31;     // m = col within tile
      const float* s = Wih + (size_t)(nb*64 + m)*HH + k8*8;
      float4 x0 = *(const float4*)s, x1 = *(const float4*)(s+4);
      union { unsigned short u[8]; uint4 v; } o;
      o.u[0]=f2bf(x0.x); o.u[1]=f2bf(x0.y); o.u[2]=f2bf(x0.z); o.u[3]=f2bf(x0.w);
      o.u[4]=f2bf(x1.x); o.u[5]=f2bf(x1.y); o.u[6]=f2bf(x1.z); o.u[7]=f2bf(x1.w);
      *(uint4*)&B_l[(m << 8) + ((k8*8) ^ ((m & 7) << 3))] = o.v;
    }
    __syncthreads();

    f32x4 acc[2][4];
#pragma unroll
    for (int mt = 0; mt < 2; ++mt)
#pragma unroll
      for (int nt = 0; nt < 4; ++nt) acc[mt][nt] = (f32x4){0.f,0.f,0.f,0.f};

#pragma unroll
    for (int kt = 0; kt < 8; ++kt){
      bf16x8 a0 = afrag(A_l, w*2+0, kt, nl, kq);
      bf16x8 a1 = afrag(A_l, w*2+1, kt, nl, kq);
#pragma unroll
      for (int nt = 0; nt < 4; ++nt){
        bf16x8 bv = afrag(B_l, nt, kt, nl, kq);
        acc[0][nt] = __builtin_amdgcn_mfma_f32_16x16x32_bf16(a0, bv, acc[0][nt], 0,0,0);
        acc[1][nt] = __builtin_amdgcn_mfma_f32_16x16x32_bf16(a1, bv, acc[1][nt], 0,0,0);
      }
    }

    // store to [t][col][b]: rows r=0..3 are consecutive b
#pragma unroll
    for (int mt = 0; mt < 2; ++mt)
#pragma unroll
      for (int nt = 0; nt < 4; ++nt){
        int p0 = pbase + w*32 + mt*16 + kq*4;
        int t = p0 >> 6, b0 = p0 & 63;
        int col = nb*64 + nt*16 + nl;
        union { unsigned short u[4]; uint2 v; } o;
        o.u[0]=f2bf(acc[mt][nt][0]); o.u[1]=f2bf(acc[mt][nt][1]);
        o.u[2]=f2bf(acc[mt][nt][2]); o.u[3]=f2bf(acc[mt][nt][3]);
        *(uint2*)(gxd + ((size_t)t*1024 + col)*64 + b0) = o.v;
      }
  }
}

// ---------------- persistent bidirectional LSTM, barrier-free, MALL-coherent exchange ----------------
// 32 blocks: 16 fwd + 16 bwd. WG wg owns h-cols wg*16..+15. Wave w owns batch rows w*16..+15
// and computes ALL 4 gates for them (gate combine is lane-local, no cross-wave exchange).
// Flags: one dword per producer (no RMW); consumer polls one coalesced 64B line.
__global__ __launch_bounds__(256,1) void k_lstm(
    const unsigned short* __restrict__ gx,
    const float* __restrict__ Whh_f, const float* __restrict__ bih_f, const float* __restrict__ bhh_f,
    const float* __restrict__ Whh_b, const float* __restrict__ bih_b, const float* __restrict__ bhh_b,
    unsigned short* __restrict__ hf, unsigned short* __restrict__ hb,
    unsigned int* flg)
{
  __shared__ unsigned short hstage[4][16][16];   // per-wave 16x16 transpose tile

  const int tid  = threadIdx.x;
  const int lane = tid & 63;
  const int w    = tid >> 6;           // wave: batch rows w*16..+15
  const int dir  = blockIdx.x >> 4;
  const int wg   = blockIdx.x & 15;
  const int nl   = lane & 15;
  const int kq   = lane >> 4;

  const float* Whh = dir ? Whh_b : Whh_f;
  const float* bih = dir ? bih_b : bih_f;
  const float* bhh = dir ? bhh_b : bhh_f;
  unsigned short* hbuf = dir ? hb : hf;
  const unsigned short* gxd = gx + (size_t)dir*SS*1024*64;
  unsigned int* myflg = flg + (size_t)dir*SS*4*16;

  // B-fragments: wf[nt][kt], gate col = nt*256 + wg*16 + nl  (128 VGPRs)
  bf16x8 wf[4][8];
#pragma unroll
  for (int nt = 0; nt < 4; ++nt)
#pragma unroll
    for (int kt = 0; kt < 8; ++kt){
      const float* p = Whh + (size_t)(nt*256 + wg*16 + nl)*HH + kt*32 + kq*4;
      float4 lo = *(const float4*)p;
      float4 hi = *(const float4*)(p + 16);
      bf16x8 f;
      f[0]=(short)f2bf(lo.x); f[1]=(short)f2bf(lo.y); f[2]=(short)f2bf(lo.z); f[3]=(short)f2bf(lo.w);
      f[4]=(short)f2bf(hi.x); f[5]=(short)f2bf(hi.y); f[6]=(short)f2bf(hi.z); f[7]=(short)f2bf(hi.w);
      wf[nt][kt] = f;
    }

  float bias[4];
#pragma unroll
  for (int g = 0; g < 4; ++g){
    int col = g*256 + wg*16 + nl;
    bias[g] = bih[col] + bhh[col];
  }

  float c[4] = {0.f,0.f,0.f,0.f};   // batches w*16+kq*4+r, col wg*16+nl

  for (int s = 0; s < SS; ++s){
    const int t = dir ? (SS-1-s) : s;

    // gx prefetch (plain cached loads; independent of recurrence)
    union { uint2 v; unsigned short u[4]; } gxu[4];
#pragma unroll
    for (int g = 0; g < 4; ++g)
      gxu[g].v = *(const uint2*)(gxd + ((size_t)t*1024 + g*256 + wg*16 + nl)*64 + w*16 + kq*4);

    // wait for the 16 wave-class-w producers of step s-1:
    // one coalesced 64B flag-line load per poll, s_sleep between polls
    if (s > 0){
      const unsigned int* fb = myflg + (size_t)((s-1)*4 + w)*16;
      int guard = 0;
      for (;;){
        unsigned int f = __hip_atomic_load(fb + (lane & 15), __ATOMIC_RELAXED, __HIP_MEMORY_SCOPE_AGENT);
        if (__ballot(f != 0) == ~0ull) break;
        __builtin_amdgcn_s_sleep(1);
        if (++guard > (1 << 16)) break;
      }
      asm volatile("" ::: "memory");
    }

    // h_prev A-fragments: row = w*16+nl, direct global->VGPR via sc-flagged loads
    const int rslot = dir ? (t + 1) : s;
    const unsigned long long* hr =
      (const unsigned long long*)(hbuf + (size_t)rslot*BB*HH + (size_t)(w*16 + nl)*HH);
    bf16x8 af[8];
#pragma unroll
    for (int kt = 0; kt < 8; ++kt){
      unsigned long long lo = __hip_atomic_load(hr + kt*8 + kq,     __ATOMIC_RELAXED, __HIP_MEMORY_SCOPE_AGENT);
      unsigned long long hi = __hip_atomic_load(hr + kt*8 + kq + 4, __ATOMIC_RELAXED, __HIP_MEMORY_SCOPE_AGENT);
      union { unsigned long long u; short4v s4; } L, H;
      L.u = lo; H.u = hi;
      bf16x8 f = {L.s4[0],L.s4[1],L.s4[2],L.s4[3],H.s4[0],H.s4[1],H.s4[2],H.s4[3]};
      af[kt] = f;
    }

    f32x4 acc[4];
#pragma unroll
    for (int nt = 0; nt < 4; ++nt) acc[nt] = (f32x4){0.f,0.f,0.f,0.f};
#pragma unroll
    for (int kt = 0; kt < 8; ++kt)
#pragma unroll
      for (int nt = 0; nt < 4; ++nt)
        acc[nt] = __builtin_amdgcn_mfma_f32_16x16x32_bf16(af[kt], wf[nt][kt], acc[nt], 0,0,0);

    // lane-local gate combine: D lane(nl,kq) reg r -> batch w*16+kq*4+r, col wg*16+nl
#pragma unroll
    for (int r = 0; r < 4; ++r){
      float iv = acc[0][r] + bf2f(gxu[0].u[r]) + bias[0];
      float fv = acc[1][r] + bf2f(gxu[1].u[r]) + bias[1];
      float gv = acc[2][r] + bf2f(gxu[2].u[r]) + bias[2];
      float ov = acc[3][r] + bf2f(gxu[3].u[r]) + bias[3];
      float cc = sigm(fv)*c[r] + sigm(iv)*ftanh(gv);
      c[r] = cc;
      hstage[w][kq*4 + r][nl] = f2bf(sigm(ov)*ftanh(cc));
    }

    // same-wave 16x16 transpose through LDS -> one 8B coherent store per lane
    unsigned long long hv = *(const unsigned long long*)&hstage[w][lane & 15][(lane >> 4)*4];
    const int wslot = dir ? t : (s + 1);
    unsigned long long* dst =
      (unsigned long long*)(hbuf + (size_t)wslot*BB*HH + (size_t)(w*16 + (lane & 15))*HH + wg*16 + (lane >> 4)*4);
    __hip_atomic_store(dst, hv, __ATOMIC_RELAXED, __HIP_MEMORY_SCOPE_AGENT);

    asm volatile("s_waitcnt vmcnt(0)" ::: "memory");   // h stores complete at MALL
    if (lane == 0)
      __hip_atomic_store(myflg + (size_t)(s*4 + w)*16 + wg, 1u,
                         __ATOMIC_RELAXED, __HIP_MEMORY_SCOPE_AGENT);
  }
}

// ---------------- FC via MFMA: logits[p][tag] = [hf(t+1);hb(t)] . fcW[tag] + fcb ----------------
__global__ __launch_bounds__(256,1) void k_fc(
    const unsigned short* __restrict__ hf, const unsigned short* __restrict__ hb,
    const float* __restrict__ fcW, const float* __restrict__ fcb,
    float* __restrict__ logits)
{
  __shared__ unsigned short Bs[32][520];
  __shared__ float fcb_s[32];
  const int tid = threadIdx.x;
  for (int i = tid; i < 32*512; i += 256){
    int tg = i >> 9, k = i & 511;
    Bs[tg][k] = f2bf(fcW[tg*512 + k]);
  }
  if (tid < 32) fcb_s[tid] = fcb[tid];
  __syncthreads();

  const int lane = tid & 63, w = tid >> 6;
  const int nl = lane & 15, kq = lane >> 4;
  const int pbase = blockIdx.x * 128;

  f32x4 acc[2][2];
#pragma unroll
  for (int mt = 0; mt < 2; ++mt)
#pragma unroll
    for (int nt = 0; nt < 2; ++nt) acc[mt][nt] = (f32x4){0.f,0.f,0.f,0.f};

#pragma unroll
  for (int kt = 0; kt < 16; ++kt){
    int k0 = kt*32 + kq*4;
    bf16x8 a[2];
#pragma unroll
    for (int mt = 0; mt < 2; ++mt){
      int p = pbase + w*32 + mt*16 + nl;
      int t = p >> 6, b = p & 63;
      const unsigned short* hrp = (kt < 8)
        ? hf + (size_t)((t+1)*BB + b)*HH + k0
        : hb + (size_t)(t*BB + b)*HH + (k0 - 256);
      short4v lo = *(const short4v*)hrp;
      short4v hi = *(const short4v*)(hrp + 16);
      bf16x8 f = {lo[0],lo[1],lo[2],lo[3],hi[0],hi[1],hi[2],hi[3]};
      a[mt] = f;
    }
#pragma unroll
    for (int nt = 0; nt < 2; ++nt){
      const unsigned short* br = &Bs[nt*16 + nl][k0];
      short4v lo = *(const short4v*)br;
      short4v hi = *(const short4v*)(br + 16);
      bf16x8 bv = {lo[0],lo[1],lo[2],lo[3],hi[0],hi[1],hi[2],hi[3]};
      acc[0][nt] = __builtin_amdgcn_mfma_f32_16x16x32_bf16(a[0], bv, acc[0][nt], 0,0,0);
      acc[1][nt] = __builtin_amdgcn_mfma_f32_16x16x32_bf16(a[1], bv, acc[1][nt], 0,0,0);
    }
  }
#pragma unroll
  for (int mt = 0; mt < 2; ++mt)
#pragma unroll
    for (int nt = 0; nt < 2; ++nt)
#pragma unroll
      for (int r = 0; r < 4; ++r){
        int p = pbase + w*32 + mt*16 + kq*4 + r;
        int tg = nt*16 + nl;
        logits[(size_t)p*TT + tg] = acc[mt][nt][r] + fcb_s[tg];
      }
}

// ---------------- merged CRF: blocks 0-15 den, 16-31 vit, 32-47 num ----------------
__global__ void k_crf(const float* __restrict__ logits, const int* __restrict__ mask,
                      const int* __restrict__ labels,
                      const float* __restrict__ start, const float* __restrict__ endt,
                      const float* __restrict__ trans,
                      float* __restrict__ den, float* __restrict__ num,
                      unsigned char* __restrict__ vhist, float* __restrict__ preds)
{
  __shared__ float tr[1024];
  const int tid = threadIdx.x;
  const int role = blockIdx.x >> 4;
  const int bq   = blockIdx.x & 15;
  if (role != 2){
    for (int i = tid; i < 1024; i += 256) tr[i] = trans[i];
    __syncthreads();
  }
  const int lane = tid & 63, w = tid >> 6;
  const int b = bq*4 + w;
  const int grp = lane >> 5, tp = lane & 31;

  if (role == 0){ // denominator
    float score = start[tp] + logits[(size_t)b*TT + tp];
    for (int s = 1; s < SS; ++s){
      float m = -1e30f;
#pragma unroll
      for (int jj = 0; jj < 16; ++jj){
        int j = grp*16 + jj;
        float v = __shfl(score, j) + tr[j*32 + tp];
        m = fmaxf(m, v);
      }
      m = fmaxf(m, __shfl_xor(m, 32));
      float ssum = 0.f;
#pragma unroll
      for (int jj = 0; jj < 16; ++jj){
        int j = grp*16 + jj;
        float v = __shfl(score, j) + tr[j*32 + tp];
        ssum += __expf(v - m);
      }
      ssum += __shfl_xor(ssum, 32);
      float ns = m + __logf(ssum) + logits[(size_t)(s*BB + b)*TT + tp];
      score = mask[b*SS + s] ? ns : score;
    }
    float v = score + endt[tp];
    float mm = v;
    for (int d = 1; d < 32; d <<= 1) mm = fmaxf(mm, __shfl_xor(mm, d));
    float se = __expf(v - mm);
    for (int d = 1; d < 32; d <<= 1) se += __shfl_xor(se, d);
    if (lane == 0) den[b] = mm + __logf(se);
  } else if (role == 1){ // viterbi
    float score = start[tp] + logits[(size_t)b*TT + tp];
    for (int s = 1; s < SS; ++s){
      float m = -1e30f; int am = 0;
#pragma unroll
      for (int jj = 0; jj < 16; ++jj){
        int j = grp*16 + jj;
        float v = __shfl(score, j) + tr[j*32 + tp];
        if (v > m){ m = v; am = j; }
      }
      float om = __shfl_xor(m, 32); int oam = __shfl_xor(am, 32);
      if (om > m || (om == m && oam < am)){ m = om; am = oam; }
      int mk = mask[b*SS + s];
      float ns = m + logits[(size_t)(s*BB + b)*TT + tp];
      int idx = mk ? am : tp;
      if (grp == 0) vhist[(size_t)(s*BB + b)*32 + tp] = (unsigned char)idx;
      score = mk ? ns : score;
    }
    float v = score + endt[tp]; int a = tp;
    for (int d = 1; d < 32; d <<= 1){
      float ov = __shfl_xor(v, d); int oa = __shfl_xor(a, d);
      if (ov > v || (ov == v && oa < a)){ v = ov; a = oa; }
    }
    int tag = __shfl(a, 0);
    if (lane == 0) preds[(size_t)b*SS + SS - 1] = (float)tag;
    for (int s = SS - 1; s >= 1; --s){
      int rv = vhist[(size_t)(s*BB + b)*32 + tp];
      int pv = __shfl(rv, tag);
      if (lane == 0) preds[(size_t)b*SS + s - 1] = (float)pv;
      tag = pv;
    }
  } else { // numerator
    float acc = 0.f; int mcnt = 0;
    for (int s = lane; s < SS; s += 64){
      int mk = mask[b*SS + s];
      mcnt += mk;
      if (s >= 1){
        int tg = labels[b*SS + s], tpp = labels[b*SS + s - 1];
        float v = trans[tpp*32 + tg] + logits[(size_t)(s*BB + b)*TT + tg];
        acc += mk ? v : 0.f;
      }
    }
    for (int d = 1; d < 64; d <<= 1){ acc += __shfl_xor(acc, d); mcnt += __shfl_xor(mcnt, d); }
    if (lane == 0){
      int t0 = labels[b*SS];
      int tl = labels[b*SS + (mcnt - 1)];
      num[b] = start[t0] + logits[(size_t)b*TT + t0] + acc + endt[tl];
    }
  }
}

// ---------------- loss ----------------
__global__ void k_loss(const float* __restrict__ num, const float* __restrict__ den,
                       float* __restrict__ out)
{
  int l = threadIdx.x;
  float v = num[l] - den[l];
  for (int d = 1; d < 64; d <<= 1) v += __shfl_xor(v, d);
  if (l == 0) out[BB*SS] = -v;
}

extern "C" void kernel_launch(void* const* d_in, const int* in_sizes, int n_in,
                              void* d_out, int out_size, void* d_ws, size_t ws_size,
                              hipStream_t stream)
{
  const int*   seq       = (const int*)  d_in[0];
  const int*   mask      = (const int*)  d_in[1];
  const int*   labels    = (const int*)  d_in[2];
  const float* embedding = (const float*)d_in[3];
  const float* Wih_f     = (const float*)d_in[4];
  const float* Whh_f     = (const float*)d_in[5];
  const float* bih_f     = (const float*)d_in[6];
  const float* bhh_f     = (const float*)d_in[7];
  const float* Wih_b     = (const float*)d_in[8];
  const float* Whh_b     = (const float*)d_in[9];
  const float* bih_b     = (const float*)d_in[10];
  const float* bhh_b     = (const float*)d_in[11];
  const float* fcW       = (const float*)d_in[12];
  const float* fcb       = (const float*)d_in[13];
  const float* start_t   = (const float*)d_in[14];
  const float* end_t     = (const float*)d_in[15];
  const float* trans     = (const float*)d_in[16];

  char* ws = (char*)d_ws;
  size_t off = 0;
  unsigned short* gxb = (unsigned short*)(ws + off); off += (size_t)2*SS*1024*64*2;     // 128 MiB
  unsigned short* hf  = (unsigned short*)(ws + off); off += (size_t)(SS+1)*BB*HH*2;     // 16 MiB
  unsigned short* hb  = (unsigned short*)(ws + off); off += (size_t)(SS+1)*BB*HH*2;     // 16 MiB
  float*          lgt = (float*)(ws + off);          off += (size_t)SS*BB*TT*4;         // 4 MiB
  unsigned char*  vh  = (unsigned char*)(ws + off);  off += (size_t)SS*BB*TT;           // 1 MiB
  float*          den = (float*)(ws + off);          off += 256;
  float*          num = (float*)(ws + off);          off += 256;
  unsigned int*   flg = (unsigned int*)(ws + off);   off += (size_t)2*SS*4*16*4;        // 256 KiB

  hipMemsetAsync(hf, 0, (size_t)BB*HH*2, stream);
  hipMemsetAsync(hb + (size_t)SS*BB*HH, 0, (size_t)BB*HH*2, stream);
  hipMemsetAsync(flg, 0, (size_t)2*SS*4*16*4, stream);

  k_xgemm<<<dim3(256,2), 256, 0, stream>>>(seq, embedding, Wih_f, Wih_b, gxb);
  k_lstm<<<32, 256, 0, stream>>>(gxb, Whh_f, bih_f, bhh_f, Whh_b, bih_b, bhh_b, hf, hb, flg);
  k_fc<<<256, 256, 0, stream>>>(hf, hb, fcW, fcb, lgt);
  k_crf<<<48, 256, 0, stream>>>(lgt, mask, labels, start_t, end_t, trans, den, num, vh, (float*)d_out);
  k_loss<<<1, 64, 0, stream>>>(num, den, (float*)d_out);
}

// Round 5
// 3113.402 us; speedup vs baseline: 1.5798x; 1.0085x over previous
//
#include <hip/hip_runtime.h>
#include <stdint.h>

#define SS 512
#define BB 64
#define HH 256
#define TT 32

typedef __attribute__((ext_vector_type(8))) short bf16x8;
typedef __attribute__((ext_vector_type(4))) short short4v;
typedef __attribute__((ext_vector_type(4))) float f32x4;

__device__ __forceinline__ unsigned short f2bf(float f){
  unsigned u = __float_as_uint(f);
  unsigned r = (u + 0x7FFFu + ((u >> 16) & 1u)) >> 16;
  return (unsigned short)r;
}
__device__ __forceinline__ float bf2f(unsigned short s){
  return __uint_as_float(((unsigned)s) << 16);
}
__device__ __forceinline__ float sigm(float x){ return 1.0f/(1.0f+__expf(-x)); }
__device__ __forceinline__ float ftanh(float x){
  float e = __expf(2.f*x);
  return 1.f - 2.f/(e + 1.f);
}

// swizzled-LDS fragment read (used by k_xgemm only)
__device__ __forceinline__ bf16x8 afrag(const unsigned short* A, int mt, int ktp, int nl, int kq){
  int m = mt*16 + nl;
  int sw = (m & 7) << 3;
  int kk = ktp*32 + kq*4;
  short4v lo = *(const short4v*)(A + (m << 8) + (kk ^ sw));
  short4v hi = *(const short4v*)(A + (m << 8) + ((kk + 16) ^ sw));
  bf16x8 r = {lo[0],lo[1],lo[2],lo[3],hi[0],hi[1],hi[2],hi[3]};
  return r;
}

// ---------------- fused gather + x@Wih^T GEMM -> gx bf16 [dir][t][col(1024)][b(64)] ----------------
__global__ __launch_bounds__(256,1) void k_xgemm(
    const int* __restrict__ seq, const float* __restrict__ emb,
    const float* __restrict__ Wih_f, const float* __restrict__ Wih_b,
    unsigned short* __restrict__ gx)
{
  __shared__ __align__(16) unsigned short A_l[128*256];  // 64 KiB
  __shared__ __align__(16) unsigned short B_l[64*256];   // 32 KiB

  const int tid = threadIdx.x;
  const int lane = tid & 63, w = tid >> 6;
  const int nl = lane & 15, kq = lane >> 4;
  const int pbase = blockIdx.x * 128;
  const int dir = blockIdx.y;
  const float* Wih = dir ? Wih_b : Wih_f;
  unsigned short* gxd = gx + (size_t)dir*SS*1024*64;

  // stage A: 128 rows (p = t*64+b), gather embedding rows, f32->bf16
#pragma unroll
  for (int i = 0; i < 16; ++i){
    int c = tid + i*256;
    int m = c >> 5, k8 = c & 31;
    int p = pbase + m, t = p >> 6, b = p & 63;
    int er = seq[b*SS + t];
    const float* s = emb + (size_t)er*HH + k8*8;
    float4 x0 = *(const float4*)s, x1 = *(const float4*)(s+4);
    union { unsigned short u[8]; uint4 v; } o;
    o.u[0]=f2bf(x0.x); o.u[1]=f2bf(x0.y); o.u[2]=f2bf(x0.z); o.u[3]=f2bf(x0.w);
    o.u[4]=f2bf(x1.x); o.u[5]=f2bf(x1.y); o.u[6]=f2bf(x1.z); o.u[7]=f2bf(x1.w);
    *(uint4*)&A_l[(m << 8) + ((k8*8) ^ ((m & 7) << 3))] = o.v;
  }

  for (int nb = 0; nb < 16; ++nb){
    __syncthreads();
#pragma unroll
    for (int i = 0; i < 8; ++i){
      int c = tid + i*256;
      int m = c >> 5, k8 = c & 31;     // m = col within tile
      const float* s = Wih + (size_t)(nb*64 + m)*HH + k8*8;
      float4 x0 = *(const float4*)s, x1 = *(const float4*)(s+4);
      union { unsigned short u[8]; uint4 v; } o;
      o.u[0]=f2bf(x0.x); o.u[1]=f2bf(x0.y); o.u[2]=f2bf(x0.z); o.u[3]=f2bf(x0.w);
      o.u[4]=f2bf(x1.x); o.u[5]=f2bf(x1.y); o.u[6]=f2bf(x1.z); o.u[7]=f2bf(x1.w);
      *(uint4*)&B_l[(m << 8) + ((k8*8) ^ ((m & 7) << 3))] = o.v;
    }
    __syncthreads();

    f32x4 acc[2][4];
#pragma unroll
    for (int mt = 0; mt < 2; ++mt)
#pragma unroll
      for (int nt = 0; nt < 4; ++nt) acc[mt][nt] = (f32x4){0.f,0.f,0.f,0.f};

#pragma unroll
    for (int kt = 0; kt < 8; ++kt){
      bf16x8 a0 = afrag(A_l, w*2+0, kt, nl, kq);
      bf16x8 a1 = afrag(A_l, w*2+1, kt, nl, kq);
#pragma unroll
      for (int nt = 0; nt < 4; ++nt){
        bf16x8 bv = afrag(B_l, nt, kt, nl, kq);
        acc[0][nt] = __builtin_amdgcn_mfma_f32_16x16x32_bf16(a0, bv, acc[0][nt], 0,0,0);
        acc[1][nt] = __builtin_amdgcn_mfma_f32_16x16x32_bf16(a1, bv, acc[1][nt], 0,0,0);
      }
    }

    // store to [t][col][b]: rows r=0..3 are consecutive b
#pragma unroll
    for (int mt = 0; mt < 2; ++mt)
#pragma unroll
      for (int nt = 0; nt < 4; ++nt){
        int p0 = pbase + w*32 + mt*16 + kq*4;
        int t = p0 >> 6, b0 = p0 & 63;
        int col = nb*64 + nt*16 + nl;
        union { unsigned short u[4]; uint2 v; } o;
        o.u[0]=f2bf(acc[mt][nt][0]); o.u[1]=f2bf(acc[mt][nt][1]);
        o.u[2]=f2bf(acc[mt][nt][2]); o.u[3]=f2bf(acc[mt][nt][3]);
        *(uint2*)(gxd + ((size_t)t*1024 + col)*64 + b0) = o.v;
      }
  }
}

// ---------------- persistent bidirectional LSTM, barrier-free, MALL-coherent exchange ----------------
// 32 blocks: 16 fwd + 16 bwd. WG wg owns h-cols wg*16..+15. Wave w owns batch rows w*16..+15
// and computes ALL 4 gates for them (gate combine is lane-local, no cross-wave exchange).
// Flags: one dword per producer (no RMW); consumer polls one coalesced 64B line.
__global__ __launch_bounds__(256,1) void k_lstm(
    const unsigned short* __restrict__ gx,
    const float* __restrict__ Whh_f, const float* __restrict__ bih_f, const float* __restrict__ bhh_f,
    const float* __restrict__ Whh_b, const float* __restrict__ bih_b, const float* __restrict__ bhh_b,
    unsigned short* __restrict__ hf, unsigned short* __restrict__ hb,
    unsigned int* flg)
{
  __shared__ unsigned short hstage[4][16][16];   // per-wave 16x16 transpose tile

  const int tid  = threadIdx.x;
  const int lane = tid & 63;
  const int w    = tid >> 6;           // wave: batch rows w*16..+15
  const int dir  = blockIdx.x >> 4;
  const int wg   = blockIdx.x & 15;
  const int nl   = lane & 15;
  const int kq   = lane >> 4;

  const float* Whh = dir ? Whh_b : Whh_f;
  const float* bih = dir ? bih_b : bih_f;
  const float* bhh = dir ? bhh_b : bhh_f;
  unsigned short* hbuf = dir ? hb : hf;
  const unsigned short* gxd = gx + (size_t)dir*SS*1024*64;
  unsigned int* myflg = flg + (size_t)dir*SS*4*16;

  // B-fragments: wf[nt][kt], gate col = nt*256 + wg*16 + nl  (128 VGPRs)
  bf16x8 wf[4][8];
#pragma unroll
  for (int nt = 0; nt < 4; ++nt)
#pragma unroll
    for (int kt = 0; kt < 8; ++kt){
      const float* p = Whh + (size_t)(nt*256 + wg*16 + nl)*HH + kt*32 + kq*4;
      float4 lo = *(const float4*)p;
      float4 hi = *(const float4*)(p + 16);
      bf16x8 f;
      f[0]=(short)f2bf(lo.x); f[1]=(short)f2bf(lo.y); f[2]=(short)f2bf(lo.z); f[3]=(short)f2bf(lo.w);
      f[4]=(short)f2bf(hi.x); f[5]=(short)f2bf(hi.y); f[6]=(short)f2bf(hi.z); f[7]=(short)f2bf(hi.w);
      wf[nt][kt] = f;
    }

  float bias[4];
#pragma unroll
  for (int g = 0; g < 4; ++g){
    int col = g*256 + wg*16 + nl;
    bias[g] = bih[col] + bhh[col];
  }

  float c[4] = {0.f,0.f,0.f,0.f};   // batches w*16+kq*4+r, col wg*16+nl

  for (int s = 0; s < SS; ++s){
    const int t = dir ? (SS-1-s) : s;

    // gx prefetch (plain cached loads; independent of recurrence)
    union { uint2 v; unsigned short u[4]; } gxu[4];
#pragma unroll
    for (int g = 0; g < 4; ++g)
      gxu[g].v = *(const uint2*)(gxd + ((size_t)t*1024 + g*256 + wg*16 + nl)*64 + w*16 + kq*4);

    // wait for the 16 wave-class-w producers of step s-1:
    // one coalesced 64B flag-line load per poll, s_sleep between polls
    if (s > 0){
      const unsigned int* fb = myflg + (size_t)((s-1)*4 + w)*16;
      int guard = 0;
      for (;;){
        unsigned int f = __hip_atomic_load(fb + (lane & 15), __ATOMIC_RELAXED, __HIP_MEMORY_SCOPE_AGENT);
        if (__ballot(f != 0) == ~0ull) break;
        __builtin_amdgcn_s_sleep(1);
        if (++guard > (1 << 16)) break;
      }
      asm volatile("" ::: "memory");
    }

    // h_prev A-fragments: row = w*16+nl, direct global->VGPR via sc-flagged loads
    const int rslot = dir ? (t + 1) : s;
    const unsigned long long* hr =
      (const unsigned long long*)(hbuf + (size_t)rslot*BB*HH + (size_t)(w*16 + nl)*HH);
    bf16x8 af[8];
#pragma unroll
    for (int kt = 0; kt < 8; ++kt){
      unsigned long long lo = __hip_atomic_load(hr + kt*8 + kq,     __ATOMIC_RELAXED, __HIP_MEMORY_SCOPE_AGENT);
      unsigned long long hi = __hip_atomic_load(hr + kt*8 + kq + 4, __ATOMIC_RELAXED, __HIP_MEMORY_SCOPE_AGENT);
      union { unsigned long long u; short4v s4; } L, H;
      L.u = lo; H.u = hi;
      bf16x8 f = {L.s4[0],L.s4[1],L.s4[2],L.s4[3],H.s4[0],H.s4[1],H.s4[2],H.s4[3]};
      af[kt] = f;
    }

    f32x4 acc[4];
#pragma unroll
    for (int nt = 0; nt < 4; ++nt) acc[nt] = (f32x4){0.f,0.f,0.f,0.f};
#pragma unroll
    for (int kt = 0; kt < 8; ++kt)
#pragma unroll
      for (int nt = 0; nt < 4; ++nt)
        acc[nt] = __builtin_amdgcn_mfma_f32_16x16x32_bf16(af[kt], wf[nt][kt], acc[nt], 0,0,0);

    // lane-local gate combine: D lane(nl,kq) reg r -> batch w*16+kq*4+r, col wg*16+nl
#pragma unroll
    for (int r = 0; r < 4; ++r){
      float iv = acc[0][r] + bf2f(gxu[0].u[r]) + bias[0];
      float fv = acc[1][r] + bf2f(gxu[1].u[r]) + bias[1];
      float gv = acc[2][r] + bf2f(gxu[2].u[r]) + bias[2];
      float ov = acc[3][r] + bf2f(gxu[3].u[r]) + bias[3];
      float cc = sigm(fv)*c[r] + sigm(iv)*ftanh(gv);
      c[r] = cc;
      hstage[w][kq*4 + r][nl] = f2bf(sigm(ov)*ftanh(cc));
    }

    // same-wave 16x16 transpose through LDS -> one 8B coherent store per lane
    unsigned long long hv = *(const unsigned long long*)&hstage[w][lane & 15][(lane >> 4)*4];
    const int wslot = dir ? t : (s + 1);
    unsigned long long* dst =
      (unsigned long long*)(hbuf + (size_t)wslot*BB*HH + (size_t)(w*16 + (lane & 15))*HH + wg*16 + (lane >> 4)*4);
    __hip_atomic_store(dst, hv, __ATOMIC_RELAXED, __HIP_MEMORY_SCOPE_AGENT);

    asm volatile("s_waitcnt vmcnt(0)" ::: "memory");   // h stores complete at MALL
    if (lane == 0)
      __hip_atomic_store(myflg + (size_t)(s*4 + w)*16 + wg, 1u,
                         __ATOMIC_RELAXED, __HIP_MEMORY_SCOPE_AGENT);
  }
}

// ---------------- FC via MFMA: logits[p][tag] = [hf(t+1);hb(t)] . fcW[tag] + fcb ----------------
__global__ __launch_bounds__(256,1) void k_fc(
    const unsigned short* __restrict__ hf, const unsigned short* __restrict__ hb,
    const float* __restrict__ fcW, const float* __restrict__ fcb,
    float* __restrict__ logits)
{
  __shared__ unsigned short Bs[32][520];
  __shared__ float fcb_s[32];
  const int tid = threadIdx.x;
  for (int i = tid; i < 32*512; i += 256){
    int tg = i >> 9, k = i & 511;
    Bs[tg][k] = f2bf(fcW[tg*512 + k]);
  }
  if (tid < 32) fcb_s[tid] = fcb[tid];
  __syncthreads();

  const int lane = tid & 63, w = tid >> 6;
  const int nl = lane & 15, kq = lane >> 4;
  const int pbase = blockIdx.x * 128;

  f32x4 acc[2][2];
#pragma unroll
  for (int mt = 0; mt < 2; ++mt)
#pragma unroll
    for (int nt = 0; nt < 2; ++nt) acc[mt][nt] = (f32x4){0.f,0.f,0.f,0.f};

#pragma unroll
  for (int kt = 0; kt < 16; ++kt){
    int k0 = kt*32 + kq*4;
    bf16x8 a[2];
#pragma unroll
    for (int mt = 0; mt < 2; ++mt){
      int p = pbase + w*32 + mt*16 + nl;
      int t = p >> 6, b = p & 63;
      const unsigned short* hrp = (kt < 8)
        ? hf + (size_t)((t+1)*BB + b)*HH + k0
        : hb + (size_t)(t*BB + b)*HH + (k0 - 256);
      short4v lo = *(const short4v*)hrp;
      short4v hi = *(const short4v*)(hrp + 16);
      bf16x8 f = {lo[0],lo[1],lo[2],lo[3],hi[0],hi[1],hi[2],hi[3]};
      a[mt] = f;
    }
#pragma unroll
    for (int nt = 0; nt < 2; ++nt){
      const unsigned short* br = &Bs[nt*16 + nl][k0];
      short4v lo = *(const short4v*)br;
      short4v hi = *(const short4v*)(br + 16);
      bf16x8 bv = {lo[0],lo[1],lo[2],lo[3],hi[0],hi[1],hi[2],hi[3]};
      acc[0][nt] = __builtin_amdgcn_mfma_f32_16x16x32_bf16(a[0], bv, acc[0][nt], 0,0,0);
      acc[1][nt] = __builtin_amdgcn_mfma_f32_16x16x32_bf16(a[1], bv, acc[1][nt], 0,0,0);
    }
  }
#pragma unroll
  for (int mt = 0; mt < 2; ++mt)
#pragma unroll
    for (int nt = 0; nt < 2; ++nt)
#pragma unroll
      for (int r = 0; r < 4; ++r){
        int p = pbase + w*32 + mt*16 + kq*4 + r;
        int tg = nt*16 + nl;
        logits[(size_t)p*TT + tg] = acc[mt][nt][r] + fcb_s[tg];
      }
}

// ---------------- merged CRF: blocks 0-15 den, 16-31 vit, 32-47 num ----------------
__global__ void k_crf(const float* __restrict__ logits, const int* __restrict__ mask,
                      const int* __restrict__ labels,
                      const float* __restrict__ start, const float* __restrict__ endt,
                      const float* __restrict__ trans,
                      float* __restrict__ den, float* __restrict__ num,
                      unsigned char* __restrict__ vhist, float* __restrict__ preds)
{
  __shared__ float tr[1024];
  const int tid = threadIdx.x;
  const int role = blockIdx.x >> 4;
  const int bq   = blockIdx.x & 15;
  if (role != 2){
    for (int i = tid; i < 1024; i += 256) tr[i] = trans[i];
    __syncthreads();
  }
  const int lane = tid & 63, w = tid >> 6;
  const int b = bq*4 + w;
  const int grp = lane >> 5, tp = lane & 31;

  if (role == 0){ // denominator
    float score = start[tp] + logits[(size_t)b*TT + tp];
    for (int s = 1; s < SS; ++s){
      float m = -1e30f;
#pragma unroll
      for (int jj = 0; jj < 16; ++jj){
        int j = grp*16 + jj;
        float v = __shfl(score, j) + tr[j*32 + tp];
        m = fmaxf(m, v);
      }
      m = fmaxf(m, __shfl_xor(m, 32));
      float ssum = 0.f;
#pragma unroll
      for (int jj = 0; jj < 16; ++jj){
        int j = grp*16 + jj;
        float v = __shfl(score, j) + tr[j*32 + tp];
        ssum += __expf(v - m);
      }
      ssum += __shfl_xor(ssum, 32);
      float ns = m + __logf(ssum) + logits[(size_t)(s*BB + b)*TT + tp];
      score = mask[b*SS + s] ? ns : score;
    }
    float v = score + endt[tp];
    float mm = v;
    for (int d = 1; d < 32; d <<= 1) mm = fmaxf(mm, __shfl_xor(mm, d));
    float se = __expf(v - mm);
    for (int d = 1; d < 32; d <<= 1) se += __shfl_xor(se, d);
    if (lane == 0) den[b] = mm + __logf(se);
  } else if (role == 1){ // viterbi
    float score = start[tp] + logits[(size_t)b*TT + tp];
    for (int s = 1; s < SS; ++s){
      float m = -1e30f; int am = 0;
#pragma unroll
      for (int jj = 0; jj < 16; ++jj){
        int j = grp*16 + jj;
        float v = __shfl(score, j) + tr[j*32 + tp];
        if (v > m){ m = v; am = j; }
      }
      float om = __shfl_xor(m, 32); int oam = __shfl_xor(am, 32);
      if (om > m || (om == m && oam < am)){ m = om; am = oam; }
      int mk = mask[b*SS + s];
      float ns = m + logits[(size_t)(s*BB + b)*TT + tp];
      int idx = mk ? am : tp;
      if (grp == 0) vhist[(size_t)(s*BB + b)*32 + tp] = (unsigned char)idx;
      score = mk ? ns : score;
    }
    float v = score + endt[tp]; int a = tp;
    for (int d = 1; d < 32; d <<= 1){
      float ov = __shfl_xor(v, d); int oa = __shfl_xor(a, d);
      if (ov > v || (ov == v && oa < a)){ v = ov; a = oa; }
    }
    int tag = __shfl(a, 0);
    if (lane == 0) preds[(size_t)b*SS + SS - 1] = (float)tag;
    for (int s = SS - 1; s >= 1; --s){
      int rv = vhist[(size_t)(s*BB + b)*32 + tp];
      int pv = __shfl(rv, tag);
      if (lane == 0) preds[(size_t)b*SS + s - 1] = (float)pv;
      tag = pv;
    }
  } else { // numerator
    float acc = 0.f; int mcnt = 0;
    for (int s = lane; s < SS; s += 64){
      int mk = mask[b*SS + s];
      mcnt += mk;
      if (s >= 1){
        int tg = labels[b*SS + s], tpp = labels[b*SS + s - 1];
        float v = trans[tpp*32 + tg] + logits[(size_t)(s*BB + b)*TT + tg];
        acc += mk ? v : 0.f;
      }
    }
    for (int d = 1; d < 64; d <<= 1){ acc += __shfl_xor(acc, d); mcnt += __shfl_xor(mcnt, d); }
    if (lane == 0){
      int t0 = labels[b*SS];
      int tl = labels[b*SS + (mcnt - 1)];
      num[b] = start[t0] + logits[(size_t)b*TT + t0] + acc + endt[tl];
    }
  }
}

// ---------------- loss ----------------
__global__ void k_loss(const float* __restrict__ num, const float* __restrict__ den,
                       float* __restrict__ out)
{
  int l = threadIdx.x;
  float v = num[l] - den[l];
  for (int d = 1; d < 64; d <<= 1) v += __shfl_xor(v, d);
  if (l == 0) out[BB*SS] = -v;
}

extern "C" void kernel_launch(void* const* d_in, const int* in_sizes, int n_in,
                              void* d_out, int out_size, void* d_ws, size_t ws_size,
                              hipStream_t stream)
{
  const int*   seq       = (const int*)  d_in[0];
  const int*   mask      = (const int*)  d_in[1];
  const int*   labels    = (const int*)  d_in[2];
  const float* embedding = (const float*)d_in[3];
  const float* Wih_f     = (const float*)d_in[4];
  const float* Whh_f     = (const float*)d_in[5];
  const float* bih_f     = (const float*)d_in[6];
  const float* bhh_f     = (const float*)d_in[7];
  const float* Wih_b     = (const float*)d_in[8];
  const float* Whh_b     = (const float*)d_in[9];
  const float* bih_b     = (const float*)d_in[10];
  const float* bhh_b     = (const float*)d_in[11];
  const float* fcW       = (const float*)d_in[12];
  const float* fcb       = (const float*)d_in[13];
  const float* start_t   = (const float*)d_in[14];
  const float* end_t     = (const float*)d_in[15];
  const float* trans     = (const float*)d_in[16];

  char* ws = (char*)d_ws;
  size_t off = 0;
  unsigned short* gxb = (unsigned short*)(ws + off); off += (size_t)2*SS*1024*64*2;     // 128 MiB
  unsigned short* hf  = (unsigned short*)(ws + off); off += (size_t)(SS+1)*BB*HH*2;     // 16 MiB
  unsigned short* hb  = (unsigned short*)(ws + off); off += (size_t)(SS+1)*BB*HH*2;     // 16 MiB
  float*          lgt = (float*)(ws + off);          off += (size_t)SS*BB*TT*4;         // 4 MiB
  unsigned char*  vh  = (unsigned char*)(ws + off);  off += (size_t)SS*BB*TT;           // 1 MiB
  float*          den = (float*)(ws + off);          off += 256;
  float*          num = (float*)(ws + off);          off += 256;
  unsigned int*   flg = (unsigned int*)(ws + off);   off += (size_t)2*SS*4*16*4;        // 256 KiB

  hipMemsetAsync(hf, 0, (size_t)BB*HH*2, stream);
  hipMemsetAsync(hb + (size_t)SS*BB*HH, 0, (size_t)BB*HH*2, stream);
  hipMemsetAsync(flg, 0, (size_t)2*SS*4*16*4, stream);

  k_xgemm<<<dim3(256,2), 256, 0, stream>>>(seq, embedding, Wih_f, Wih_b, gxb);
  k_lstm<<<32, 256, 0, stream>>>(gxb, Whh_f, bih_f, bhh_f, Whh_b, bih_b, bhh_b, hf, hb, flg);
  k_fc<<<256, 256, 0, stream>>>(hf, hb, fcW, fcb, lgt);
  k_crf<<<48, 256, 0, stream>>>(lgt, mask, labels, start_t, end_t, trans, den, num, vh, (float*)d_out);
  k_loss<<<1, 64, 0, stream>>>(num, den, (float*)d_out);
}